// Round 10
// baseline (88.153 us; speedup 1.0000x reference)
//
#include <hip/hip_runtime.h>
#include <hip/hip_fp16.h>
#include <math.h>
#include <float.h>

#define N_NODES 100000
#define N_EDGES 1200000
#define FEAT 64
#define AVG_D_LOG 2.5649493574615367f  /* log(13.0) */
#define EPS_STD 1e-5f
#define EPS_BN 1e-5
#define AGG_BLOCKS 12500               /* 2 nodes/wave * 4 waves: 12500*8 = N_NODES */
#define HN_BLOCKS 6250                 /* N_NODES*FEAT/4/256 */
#define RP_BLOCKS 391                  /* ceil((N_NODES+1)/256) */
#define OLD_RED_BLOCKS 512             /* fallback path */

#if __has_builtin(__builtin_fmaxf16)
#define H16MAX(a,b) __builtin_fmaxf16((a),(b))
#define H16MIN(a,b) __builtin_fminf16((a),(b))
#else
#define H16MAX(a,b) ((a) > (b) ? (a) : (b))
#define H16MIN(a,b) ((a) < (b) ? (a) : (b))
#endif

// ----------------------------------------------- fused hn(fp16) + rowptr ----
__global__ void __launch_bounds__(256) hn_rowptr(
    const float* __restrict__ h, const float* __restrict__ norm,
    const int* __restrict__ dst,
    __half* __restrict__ hn_h, int* __restrict__ rowptr)
{
    const int b = blockIdx.x;
    if (b < HN_BLOCKS) {
        const size_t i4 = ((size_t)b * 256 + threadIdx.x) * 4;
        const int node = (int)(i4 >> 6);
        const float nr = norm[node];
        float4 v = *reinterpret_cast<const float4*>(h + i4);
        __half2 p0 = __floats2half2_rn(v.x * nr, v.y * nr);
        __half2 p1 = __floats2half2_rn(v.z * nr, v.w * nr);
        __half2* o = reinterpret_cast<__half2*>(hn_h + i4);
        o[0] = p0; o[1] = p1;
    } else {
        const int n = (b - HN_BLOCKS) * 256 + threadIdx.x;
        if (n > N_NODES) return;
        int lo = 0, hi = N_EDGES;
        while (lo < hi) {
            int mid = (lo + hi) >> 1;
            if (dst[mid] < n) lo = mid + 1; else hi = mid;
        }
        rowptr[n] = lo;
    }
}

// ------------------------------------------------------- aggregation --------
// One wave handles TWO consecutive nodes (contiguous edge ranges). Lane =
// feature (fp16 scalar gather, SGPR base + lane offset). Dual batches keep
// 16 gathers in flight. Mixed-precision accumulate, fp16 max/min.
// BN partials written block-major float2 (coalesced 512B store per block).
template <bool WRITE_PSTAT>
__global__ void __launch_bounds__(256) pna_agg6(
    const __half* __restrict__ hn, const float* __restrict__ norm,
    const int* __restrict__ src, const int* __restrict__ rowptr,
    float* __restrict__ out, float2* __restrict__ pstat)
{
    const int tid  = threadIdx.x;
    const int wid  = tid >> 6;
    const int lane = tid & 63;
    const int n0   = (blockIdx.x * 4 + wid) * 2;       // n0, n0+1 < N_NODES

    const int s0 = __builtin_amdgcn_readfirstlane(rowptr[n0]);
    const int e0 = __builtin_amdgcn_readfirstlane(rowptr[n0 + 1]);
    const int e1 = __builtin_amdgcn_readfirstlane(rowptr[n0 + 2]);
    const int degA = e0 - s0;
    const int degB = e1 - e0;

    const _Float16* __restrict__ hnf = (const _Float16*)hn;
    const float ownA = (float)hnf[(size_t)n0 * FEAT + lane];
    const float ownB = (float)hnf[(size_t)(n0 + 1) * FEAT + lane];

    float s1A = 0.f, s2A = 0.f, s1B = 0.f, s2B = 0.f;
    _Float16 mxA = (_Float16)(-65504.f), mnA = (_Float16)(65504.f);
    _Float16 mxB = (_Float16)(-65504.f), mnB = (_Float16)(65504.f);

#define LOADW(J)  (hnf[(size_t)(J) * FEAT + lane])
#define ACCA(W) do { _Float16 w_ = (W); float f_ = (float)w_;                 \
                     s1A = __builtin_fmaf(f_, 1.0f, s1A);                     \
                     s2A = __builtin_fmaf(f_, f_, s2A);                       \
                     mxA = H16MAX(mxA, w_); mnA = H16MIN(mnA, w_); } while (0)
#define ACCB(W) do { _Float16 w_ = (W); float f_ = (float)w_;                 \
                     s1B = __builtin_fmaf(f_, 1.0f, s1B);                     \
                     s2B = __builtin_fmaf(f_, f_, s2B);                       \
                     mxB = H16MAX(mxB, w_); mnB = H16MIN(mnB, w_); } while (0)

    int ea = s0, eb = e0;
    // dual-8: 16 gathers in flight
    while (ea + 8 <= e0 && eb + 8 <= e1) {
        const int a0 = src[ea+0], a1 = src[ea+1], a2 = src[ea+2], a3 = src[ea+3];
        const int a4 = src[ea+4], a5 = src[ea+5], a6 = src[ea+6], a7 = src[ea+7];
        const int b0 = src[eb+0], b1 = src[eb+1], b2 = src[eb+2], b3 = src[eb+3];
        const int b4 = src[eb+4], b5 = src[eb+5], b6 = src[eb+6], b7 = src[eb+7];
        _Float16 wa0 = LOADW(a0), wa1 = LOADW(a1), wa2 = LOADW(a2), wa3 = LOADW(a3);
        _Float16 wa4 = LOADW(a4), wa5 = LOADW(a5), wa6 = LOADW(a6), wa7 = LOADW(a7);
        _Float16 wb0 = LOADW(b0), wb1 = LOADW(b1), wb2 = LOADW(b2), wb3 = LOADW(b3);
        _Float16 wb4 = LOADW(b4), wb5 = LOADW(b5), wb6 = LOADW(b6), wb7 = LOADW(b7);
        ACCA(wa0); ACCA(wa1); ACCA(wa2); ACCA(wa3);
        ACCA(wa4); ACCA(wa5); ACCA(wa6); ACCA(wa7);
        ACCB(wb0); ACCB(wb1); ACCB(wb2); ACCB(wb3);
        ACCB(wb4); ACCB(wb5); ACCB(wb6); ACCB(wb7);
        ea += 8; eb += 8;
    }
    // dual-4
    while (ea + 4 <= e0 && eb + 4 <= e1) {
        const int a0 = src[ea+0], a1 = src[ea+1], a2 = src[ea+2], a3 = src[ea+3];
        const int b0 = src[eb+0], b1 = src[eb+1], b2 = src[eb+2], b3 = src[eb+3];
        _Float16 wa0 = LOADW(a0), wa1 = LOADW(a1), wa2 = LOADW(a2), wa3 = LOADW(a3);
        _Float16 wb0 = LOADW(b0), wb1 = LOADW(b1), wb2 = LOADW(b2), wb3 = LOADW(b3);
        ACCA(wa0); ACCA(wa1); ACCA(wa2); ACCA(wa3);
        ACCB(wb0); ACCB(wb1); ACCB(wb2); ACCB(wb3);
        ea += 4; eb += 4;
    }
    // drain A
    for (; ea + 4 <= e0; ea += 4) {
        const int a0 = src[ea+0], a1 = src[ea+1], a2 = src[ea+2], a3 = src[ea+3];
        _Float16 w0 = LOADW(a0), w1 = LOADW(a1), w2 = LOADW(a2), w3 = LOADW(a3);
        ACCA(w0); ACCA(w1); ACCA(w2); ACCA(w3);
    }
    for (; ea < e0; ++ea) { _Float16 w = LOADW(src[ea]); ACCA(w); }
    // drain B
    for (; eb + 4 <= e1; eb += 4) {
        const int b0 = src[eb+0], b1 = src[eb+1], b2 = src[eb+2], b3 = src[eb+3];
        _Float16 w0 = LOADW(b0), w1 = LOADW(b1), w2 = LOADW(b2), w3 = LOADW(b3);
        ACCB(w0); ACCB(w1); ACCB(w2); ACCB(w3);
    }
    for (; eb < e1; ++eb) { _Float16 w = LOADW(src[eb]); ACCB(w); }
#undef ACCA
#undef ACCB
#undef LOADW

    float vA, vB;
    {
        float pre;
        if (degA > 0) {
            const float invd = 1.0f / (float)degA;
            const float mean = s1A * invd;
            const float var  = fmaxf(s2A * invd - mean * mean, 0.f);
            const float stdv = sqrtf(var + EPS_STD);
            const float logD = logf((float)degA + 1.0f);
            const float factor = norm[n0] * (1.0f + logD * (1.0f / AVG_D_LOG) + AVG_D_LOG / logD)
                                         * (1.0f / 13.0f);
            pre = ownA * (1.0f / 13.0f) + (mean + (float)mxA + (float)mnA + stdv) * factor;
        } else {
            pre = ownA * (1.0f / 13.0f);
        }
        vA = fmaxf(pre, 0.f);
    }
    {
        float pre;
        if (degB > 0) {
            const float invd = 1.0f / (float)degB;
            const float mean = s1B * invd;
            const float var  = fmaxf(s2B * invd - mean * mean, 0.f);
            const float stdv = sqrtf(var + EPS_STD);
            const float logD = logf((float)degB + 1.0f);
            const float factor = norm[n0 + 1] * (1.0f + logD * (1.0f / AVG_D_LOG) + AVG_D_LOG / logD)
                                             * (1.0f / 13.0f);
            pre = ownB * (1.0f / 13.0f) + (mean + (float)mxB + (float)mnB + stdv) * factor;
        } else {
            pre = ownB * (1.0f / 13.0f);
        }
        vB = fmaxf(pre, 0.f);
    }

    out[(size_t)n0 * FEAT + lane]       = vA;
    out[(size_t)(n0 + 1) * FEAT + lane] = vB;

    if (WRITE_PSTAT) {
        __shared__ float lsS[4][64];
        __shared__ float lsQ[4][64];
        lsS[wid][lane] = vA + vB;
        lsQ[wid][lane] = vA * vA + vB * vB;
        __syncthreads();
        if (tid < 64) {
            float2 p;
            p.x = lsS[0][tid] + lsS[1][tid] + lsS[2][tid] + lsS[3][tid];
            p.y = lsQ[0][tid] + lsQ[1][tid] + lsQ[2][tid] + lsQ[3][tid];
            pstat[(size_t)blockIdx.x * 64 + tid] = p;     // coalesced 512B/block
        }
    }
}

// ----------------- BN stats: 64 blocks, fence-free, strided read -----------
__global__ void __launch_bounds__(256) bn_stats(
    const float2* __restrict__ pstat,
    const float* __restrict__ w, const float* __restrict__ b,
    float2* __restrict__ ss)
{
    const int f   = (int)blockIdx.x;                   // 0..63
    const int tid = threadIdx.x;
    float S = 0.f, Q = 0.f;
    for (int i = tid; i < AGG_BLOCKS; i += 256) {      // stride 512B, L3-resident
        float2 p = pstat[(size_t)i * 64 + f];
        S += p.x; Q += p.y;
    }
    __shared__ double rs[256], rq[256];
    rs[tid] = (double)S; rq[tid] = (double)Q;
    __syncthreads();
    for (int s = 128; s > 0; s >>= 1) {
        if (tid < s) { rs[tid] += rs[tid + s]; rq[tid] += rq[tid + s]; }
        __syncthreads();
    }
    if (tid == 0) {
        double mu   = rs[0] / (double)N_NODES;
        double var  = rq[0] / (double)N_NODES - mu * mu;
        double rstd = 1.0 / sqrt(var + EPS_BN);
        float sc = (float)rstd * w[f];
        float2 o; o.x = sc; o.y = b[f] - (float)mu * sc;
        ss[f] = o;
    }
}

// -------------------------------------------- fallback BN stats (proven) ----
__global__ void __launch_bounds__(256) bn_partial(
    const float* __restrict__ out1,
    double* __restrict__ psum, double* __restrict__ psumsq)
{
    const int tid = threadIdx.x;
    const int fb  = tid & 15;
    const int grp = tid >> 4;
    double s0 = 0, s1 = 0, s2 = 0, s3 = 0;
    double q0 = 0, q1 = 0, q2 = 0, q3 = 0;
    for (int n = blockIdx.x * 16 + grp; n < N_NODES; n += OLD_RED_BLOCKS * 16) {
        float4 v = *reinterpret_cast<const float4*>(out1 + (size_t)n * FEAT + fb * 4);
        s0 += (double)v.x; q0 += (double)v.x * (double)v.x;
        s1 += (double)v.y; q1 += (double)v.y * (double)v.y;
        s2 += (double)v.z; q2 += (double)v.z * (double)v.z;
        s3 += (double)v.w; q3 += (double)v.w * (double)v.w;
    }
    __shared__ double ls[256 * 4];
    __shared__ double lq[256 * 4];
    ls[tid * 4 + 0] = s0; ls[tid * 4 + 1] = s1; ls[tid * 4 + 2] = s2; ls[tid * 4 + 3] = s3;
    lq[tid * 4 + 0] = q0; lq[tid * 4 + 1] = q1; lq[tid * 4 + 2] = q2; lq[tid * 4 + 3] = q3;
    __syncthreads();
    if (tid < 64) {
        const int f = tid, fblk = f >> 2, j = f & 3;
        double S = 0, Q = 0;
        for (int g = 0; g < 16; ++g) {
            S += ls[(g * 16 + fblk) * 4 + j];
            Q += lq[(g * 16 + fblk) * 4 + j];
        }
        psum  [blockIdx.x * 64 + f] = S;
        psumsq[blockIdx.x * 64 + f] = Q;
    }
}

__global__ void bn_finalize_old(const double* __restrict__ psum,
                                const double* __restrict__ psumsq,
                                const float* __restrict__ w, const float* __restrict__ b,
                                float2* __restrict__ ss)
{
    int f = threadIdx.x;                               // 64 threads
    double s = 0.0, s2 = 0.0;
    for (int blk = 0; blk < OLD_RED_BLOCKS; ++blk) {
        s  += psum  [blk * 64 + f];
        s2 += psumsq[blk * 64 + f];
    }
    double mu   = s / (double)N_NODES;
    double var  = s2 / (double)N_NODES - mu * mu;
    double rstd = 1.0 / sqrt(var + EPS_BN);
    float sc = (float)rstd * w[f];
    float2 o; o.x = sc; o.y = b[f] - (float)mu * sc;
    ss[f] = o;
}

// ------------------------------------------------------- BN apply -----------
__global__ void __launch_bounds__(256) bn_apply2(
    float* __restrict__ out, const float2* __restrict__ ss)
{
    __shared__ float sS[64], sH[64];
    if (threadIdx.x < 64) {
        float2 p = ss[threadIdx.x];
        sS[threadIdx.x] = p.x; sH[threadIdx.x] = p.y;
    }
    __syncthreads();
    const size_t i4 = ((size_t)blockIdx.x * 256 + threadIdx.x) * 4;   // grid exact
    float4 v = *reinterpret_cast<const float4*>(out + i4);
    const int f = (int)(i4 & 63);
    v.x = v.x * sS[f + 0] + sH[f + 0];
    v.y = v.y * sS[f + 1] + sH[f + 1];
    v.z = v.z * sS[f + 2] + sH[f + 2];
    v.w = v.w * sS[f + 3] + sH[f + 3];
    *reinterpret_cast<float4*>(out + i4) = v;
}

// ---------------------------------------------------------------------------
extern "C" void kernel_launch(void* const* d_in, const int* in_sizes, int n_in,
                              void* d_out, int out_size, void* d_ws, size_t ws_size,
                              hipStream_t stream) {
    const float* h    = (const float*)d_in[0];
    const float* norm = (const float*)d_in[1];
    /* d_in[2] = e, unused */
    const float* bnw  = (const float*)d_in[3];
    const float* bnb  = (const float*)d_in[4];
    const int*   src  = (const int*)d_in[5];
    const int*   dst  = (const int*)d_in[6];
    float* out = (float*)d_out;

    char* ws = (char*)d_ws;
    size_t o = 0;
    __half* hnbuf = (__half*)(ws + o);
    o += (((size_t)N_NODES * FEAT * sizeof(__half)) + 255) & ~(size_t)255;    // 12.8 MB
    int* rowptr = (int*)(ws + o);
    o += (((size_t)(N_NODES + 1) * sizeof(int)) + 255) & ~(size_t)255;        // 0.4 MB
    float2* ss = (float2*)(ws + o); o += 512;
    // new path: block-major float2 pstat[AGG_BLOCKS][64]
    float2* pstat = (float2*)(ws + o);
    const size_t need_new = o + (size_t)AGG_BLOCKS * 64 * sizeof(float2);      // +6.4 MB
    // fallback path: psum/psumsq doubles (reuse same region)
    double* psum   = (double*)(ws + o);
    double* psumsq = (double*)(ws + o + (size_t)OLD_RED_BLOCKS * 64 * sizeof(double));

    hn_rowptr<<<HN_BLOCKS + RP_BLOCKS, 256, 0, stream>>>(h, norm, dst, hnbuf, rowptr);

    if (ws_size >= need_new) {
        pna_agg6<true><<<AGG_BLOCKS, 256, 0, stream>>>(hnbuf, norm, src, rowptr, out, pstat);
        bn_stats<<<64, 256, 0, stream>>>(pstat, bnw, bnb, ss);
    } else {
        pna_agg6<false><<<AGG_BLOCKS, 256, 0, stream>>>(hnbuf, norm, src, rowptr, out, nullptr);
        bn_partial<<<OLD_RED_BLOCKS, 256, 0, stream>>>(out, psum, psumsq);
        bn_finalize_old<<<1, 64, 0, stream>>>(psum, psumsq, bnw, bnb, ss);
    }
    bn_apply2<<<HN_BLOCKS, 256, 0, stream>>>(out, ss);
}

// Round 11
// 84.264 us; speedup vs baseline: 1.0462x; 1.0462x over previous
//
#include <hip/hip_runtime.h>
#include <hip/hip_fp16.h>
#include <math.h>
#include <float.h>

#define N_NODES 100000
#define N_EDGES 1200000
#define FEAT 64
#define AVG_D_LOG 2.5649493574615367f  /* log(13.0) */
#define EPS_STD 1e-5f
#define EPS_BN 1e-5
#define AGG_BLOCKS 12500               /* 2 nodes/wave * 4 waves: 12500*8 = N_NODES */
#define HN_BLOCKS 6250                 /* N_NODES*FEAT/4/256 */
#define SC_BLOCKS 4688                 /* ceil(N_EDGES/256) edge-scatter blocks */
#define STAT1_BLOCKS 256
#define ROWS1 49                       /* ceil(12500/256) */
#define OLD_RED_BLOCKS 512             /* fallback path */

#if __has_builtin(__builtin_fmaxf16)
#define H16MAX(a,b) __builtin_fmaxf16((a),(b))
#define H16MIN(a,b) __builtin_fminf16((a),(b))
#else
#define H16MAX(a,b) ((a) > (b) ? (a) : (b))
#define H16MIN(a,b) ((a) < (b) ? (a) : (b))
#endif

// ------------------------- fused hn(fp16) + rowptr(scatter) ----------------
// Blocks [0,HN_BLOCKS): hn = (half)(h*norm), float4-in half2x2-out.
// Blocks [HN_BLOCKS,..): edge-parallel rowptr scatter — thread i fills
// rowptr[n]=i for n in (dst[i-1], dst[i]]; thread 0 fills [0..dst[0]];
// last thread fills (dst[E-1], N]. dst sorted => every entry written once.
__global__ void __launch_bounds__(256) prep(
    const float* __restrict__ h, const float* __restrict__ norm,
    const int* __restrict__ dst,
    __half* __restrict__ hn_h, int* __restrict__ rowptr)
{
    const int b = blockIdx.x;
    if (b < HN_BLOCKS) {
        const size_t i4 = ((size_t)b * 256 + threadIdx.x) * 4;
        const int node = (int)(i4 >> 6);
        const float nr = norm[node];
        float4 v = *reinterpret_cast<const float4*>(h + i4);
        __half2 p0 = __floats2half2_rn(v.x * nr, v.y * nr);
        __half2 p1 = __floats2half2_rn(v.z * nr, v.w * nr);
        __half2* o = reinterpret_cast<__half2*>(hn_h + i4);
        o[0] = p0; o[1] = p1;
    } else {
        const int i = (b - HN_BLOCKS) * 256 + threadIdx.x;
        if (i >= N_EDGES) return;
        const int d1 = dst[i];
        const int d0 = (i == 0) ? -1 : dst[i - 1];
        for (int n = d0 + 1; n <= d1; ++n) rowptr[n] = i;
        if (i == N_EDGES - 1) {
            for (int n = d1 + 1; n <= N_NODES; ++n) rowptr[n] = N_EDGES;
        }
    }
}

// ------------------------------------------------------- aggregation --------
// One wave handles TWO consecutive nodes (contiguous edge ranges). Lane =
// feature (fp16 scalar gather, SGPR base + lane offset). Dual batches keep
// 16 gathers in flight. Mixed-precision accumulate, fp16 max/min.
// BN partials written block-major float2 (coalesced 512B store per block).
template <bool WRITE_PSTAT>
__global__ void __launch_bounds__(256) pna_agg6(
    const __half* __restrict__ hn, const float* __restrict__ norm,
    const int* __restrict__ src, const int* __restrict__ rowptr,
    float* __restrict__ out, float2* __restrict__ pstat)
{
    const int tid  = threadIdx.x;
    const int wid  = tid >> 6;
    const int lane = tid & 63;
    const int n0   = (blockIdx.x * 4 + wid) * 2;       // n0, n0+1 < N_NODES

    const int s0 = __builtin_amdgcn_readfirstlane(rowptr[n0]);
    const int e0 = __builtin_amdgcn_readfirstlane(rowptr[n0 + 1]);
    const int e1 = __builtin_amdgcn_readfirstlane(rowptr[n0 + 2]);
    const int degA = e0 - s0;
    const int degB = e1 - e0;

    const _Float16* __restrict__ hnf = (const _Float16*)hn;
    const float ownA = (float)hnf[(size_t)n0 * FEAT + lane];
    const float ownB = (float)hnf[(size_t)(n0 + 1) * FEAT + lane];

    float s1A = 0.f, s2A = 0.f, s1B = 0.f, s2B = 0.f;
    _Float16 mxA = (_Float16)(-65504.f), mnA = (_Float16)(65504.f);
    _Float16 mxB = (_Float16)(-65504.f), mnB = (_Float16)(65504.f);

#define LOADW(J)  (hnf[(size_t)(J) * FEAT + lane])
#define ACCA(W) do { _Float16 w_ = (W); float f_ = (float)w_;                 \
                     s1A = __builtin_fmaf(f_, 1.0f, s1A);                     \
                     s2A = __builtin_fmaf(f_, f_, s2A);                       \
                     mxA = H16MAX(mxA, w_); mnA = H16MIN(mnA, w_); } while (0)
#define ACCB(W) do { _Float16 w_ = (W); float f_ = (float)w_;                 \
                     s1B = __builtin_fmaf(f_, 1.0f, s1B);                     \
                     s2B = __builtin_fmaf(f_, f_, s2B);                       \
                     mxB = H16MAX(mxB, w_); mnB = H16MIN(mnB, w_); } while (0)

    int ea = s0, eb = e0;
    // dual-8: 16 gathers in flight
    while (ea + 8 <= e0 && eb + 8 <= e1) {
        const int a0 = src[ea+0], a1 = src[ea+1], a2 = src[ea+2], a3 = src[ea+3];
        const int a4 = src[ea+4], a5 = src[ea+5], a6 = src[ea+6], a7 = src[ea+7];
        const int b0 = src[eb+0], b1 = src[eb+1], b2 = src[eb+2], b3 = src[eb+3];
        const int b4 = src[eb+4], b5 = src[eb+5], b6 = src[eb+6], b7 = src[eb+7];
        _Float16 wa0 = LOADW(a0), wa1 = LOADW(a1), wa2 = LOADW(a2), wa3 = LOADW(a3);
        _Float16 wa4 = LOADW(a4), wa5 = LOADW(a5), wa6 = LOADW(a6), wa7 = LOADW(a7);
        _Float16 wb0 = LOADW(b0), wb1 = LOADW(b1), wb2 = LOADW(b2), wb3 = LOADW(b3);
        _Float16 wb4 = LOADW(b4), wb5 = LOADW(b5), wb6 = LOADW(b6), wb7 = LOADW(b7);
        ACCA(wa0); ACCA(wa1); ACCA(wa2); ACCA(wa3);
        ACCA(wa4); ACCA(wa5); ACCA(wa6); ACCA(wa7);
        ACCB(wb0); ACCB(wb1); ACCB(wb2); ACCB(wb3);
        ACCB(wb4); ACCB(wb5); ACCB(wb6); ACCB(wb7);
        ea += 8; eb += 8;
    }
    // dual-4
    while (ea + 4 <= e0 && eb + 4 <= e1) {
        const int a0 = src[ea+0], a1 = src[ea+1], a2 = src[ea+2], a3 = src[ea+3];
        const int b0 = src[eb+0], b1 = src[eb+1], b2 = src[eb+2], b3 = src[eb+3];
        _Float16 wa0 = LOADW(a0), wa1 = LOADW(a1), wa2 = LOADW(a2), wa3 = LOADW(a3);
        _Float16 wb0 = LOADW(b0), wb1 = LOADW(b1), wb2 = LOADW(b2), wb3 = LOADW(b3);
        ACCA(wa0); ACCA(wa1); ACCA(wa2); ACCA(wa3);
        ACCB(wb0); ACCB(wb1); ACCB(wb2); ACCB(wb3);
        ea += 4; eb += 4;
    }
    // drain A
    for (; ea + 4 <= e0; ea += 4) {
        const int a0 = src[ea+0], a1 = src[ea+1], a2 = src[ea+2], a3 = src[ea+3];
        _Float16 w0 = LOADW(a0), w1 = LOADW(a1), w2 = LOADW(a2), w3 = LOADW(a3);
        ACCA(w0); ACCA(w1); ACCA(w2); ACCA(w3);
    }
    for (; ea < e0; ++ea) { _Float16 w = LOADW(src[ea]); ACCA(w); }
    // drain B
    for (; eb + 4 <= e1; eb += 4) {
        const int b0 = src[eb+0], b1 = src[eb+1], b2 = src[eb+2], b3 = src[eb+3];
        _Float16 w0 = LOADW(b0), w1 = LOADW(b1), w2 = LOADW(b2), w3 = LOADW(b3);
        ACCB(w0); ACCB(w1); ACCB(w2); ACCB(w3);
    }
    for (; eb < e1; ++eb) { _Float16 w = LOADW(src[eb]); ACCB(w); }
#undef ACCA
#undef ACCB
#undef LOADW

    float vA, vB;
    {
        float pre;
        if (degA > 0) {
            const float invd = 1.0f / (float)degA;
            const float mean = s1A * invd;
            const float var  = fmaxf(s2A * invd - mean * mean, 0.f);
            const float stdv = sqrtf(var + EPS_STD);
            const float logD = logf((float)degA + 1.0f);
            const float factor = norm[n0] * (1.0f + logD * (1.0f / AVG_D_LOG) + AVG_D_LOG / logD)
                                         * (1.0f / 13.0f);
            pre = ownA * (1.0f / 13.0f) + (mean + (float)mxA + (float)mnA + stdv) * factor;
        } else {
            pre = ownA * (1.0f / 13.0f);
        }
        vA = fmaxf(pre, 0.f);
    }
    {
        float pre;
        if (degB > 0) {
            const float invd = 1.0f / (float)degB;
            const float mean = s1B * invd;
            const float var  = fmaxf(s2B * invd - mean * mean, 0.f);
            const float stdv = sqrtf(var + EPS_STD);
            const float logD = logf((float)degB + 1.0f);
            const float factor = norm[n0 + 1] * (1.0f + logD * (1.0f / AVG_D_LOG) + AVG_D_LOG / logD)
                                             * (1.0f / 13.0f);
            pre = ownB * (1.0f / 13.0f) + (mean + (float)mxB + (float)mnB + stdv) * factor;
        } else {
            pre = ownB * (1.0f / 13.0f);
        }
        vB = fmaxf(pre, 0.f);
    }

    out[(size_t)n0 * FEAT + lane]       = vA;
    out[(size_t)(n0 + 1) * FEAT + lane] = vB;

    if (WRITE_PSTAT) {
        __shared__ float lsS[4][64];
        __shared__ float lsQ[4][64];
        lsS[wid][lane] = vA + vB;
        lsQ[wid][lane] = vA * vA + vB * vB;
        __syncthreads();
        if (tid < 64) {
            float2 p;
            p.x = lsS[0][tid] + lsS[1][tid] + lsS[2][tid] + lsS[3][tid];
            p.y = lsQ[0][tid] + lsQ[1][tid] + lsQ[2][tid] + lsQ[3][tid];
            pstat[(size_t)blockIdx.x * 64 + tid] = p;     // coalesced 512B/block
        }
    }
}

// ------------- BN stats stage 1: coalesced slab reduce (fixed order) -------
__global__ void __launch_bounds__(256) bn_stats1(
    const float2* __restrict__ pstat, float2* __restrict__ partial)
{
    const int tid  = threadIdx.x;
    const int w    = tid >> 6;
    const int lane = tid & 63;                         // lane == feature
    const int r0 = (int)blockIdx.x * ROWS1;
    const int r1 = min(r0 + ROWS1, AGG_BLOCKS);
    float S = 0.f, Q = 0.f;
    for (int r = r0 + w; r < r1; r += 4) {             // coalesced 512B rows
        float2 p = pstat[(size_t)r * 64 + lane];
        S += p.x; Q += p.y;
    }
    __shared__ float sS[4][64], sQ[4][64];
    sS[w][lane] = S; sQ[w][lane] = Q;
    __syncthreads();
    if (tid < 64) {
        float2 o;
        o.x = sS[0][tid] + sS[1][tid] + sS[2][tid] + sS[3][tid];
        o.y = sQ[0][tid] + sQ[1][tid] + sQ[2][tid] + sQ[3][tid];
        partial[(size_t)blockIdx.x * 64 + tid] = o;
    }
}

// ------------- BN stats stage 2: fold partials -> scale/shift --------------
__global__ void __launch_bounds__(256) bn_stats2(
    const float2* __restrict__ partial,
    const float* __restrict__ w, const float* __restrict__ b,
    float2* __restrict__ ss)
{
    const int tid = threadIdx.x;
    const int g   = tid >> 6;
    const int f   = tid & 63;
    double S = 0.0, Q = 0.0;
    for (int blk = g; blk < STAT1_BLOCKS; blk += 4) {  // fixed order per thread
        float2 p = partial[(size_t)blk * 64 + f];
        S += (double)p.x; Q += (double)p.y;
    }
    __shared__ double dS[4][64], dQ[4][64];
    dS[g][f] = S; dQ[g][f] = Q;
    __syncthreads();
    if (tid < 64) {
        double s = dS[0][tid] + dS[1][tid] + dS[2][tid] + dS[3][tid];
        double q = dQ[0][tid] + dQ[1][tid] + dQ[2][tid] + dQ[3][tid];
        double mu   = s / (double)N_NODES;
        double var  = q / (double)N_NODES - mu * mu;
        double rstd = 1.0 / sqrt(var + EPS_BN);
        float sc = (float)rstd * w[tid];
        float2 o; o.x = sc; o.y = b[tid] - (float)mu * sc;
        ss[tid] = o;
    }
}

// -------------------------------------------- fallback BN stats (proven) ----
__global__ void __launch_bounds__(256) bn_partial(
    const float* __restrict__ out1,
    double* __restrict__ psum, double* __restrict__ psumsq)
{
    const int tid = threadIdx.x;
    const int fb  = tid & 15;
    const int grp = tid >> 4;
    double s0 = 0, s1 = 0, s2 = 0, s3 = 0;
    double q0 = 0, q1 = 0, q2 = 0, q3 = 0;
    for (int n = blockIdx.x * 16 + grp; n < N_NODES; n += OLD_RED_BLOCKS * 16) {
        float4 v = *reinterpret_cast<const float4*>(out1 + (size_t)n * FEAT + fb * 4);
        s0 += (double)v.x; q0 += (double)v.x * (double)v.x;
        s1 += (double)v.y; q1 += (double)v.y * (double)v.y;
        s2 += (double)v.z; q2 += (double)v.z * (double)v.z;
        s3 += (double)v.w; q3 += (double)v.w * (double)v.w;
    }
    __shared__ double ls[256 * 4];
    __shared__ double lq[256 * 4];
    ls[tid * 4 + 0] = s0; ls[tid * 4 + 1] = s1; ls[tid * 4 + 2] = s2; ls[tid * 4 + 3] = s3;
    lq[tid * 4 + 0] = q0; lq[tid * 4 + 1] = q1; lq[tid * 4 + 2] = q2; lq[tid * 4 + 3] = q3;
    __syncthreads();
    if (tid < 64) {
        const int f = tid, fblk = f >> 2, j = f & 3;
        double S = 0, Q = 0;
        for (int g = 0; g < 16; ++g) {
            S += ls[(g * 16 + fblk) * 4 + j];
            Q += lq[(g * 16 + fblk) * 4 + j];
        }
        psum  [blockIdx.x * 64 + f] = S;
        psumsq[blockIdx.x * 64 + f] = Q;
    }
}

__global__ void bn_finalize_old(const double* __restrict__ psum,
                                const double* __restrict__ psumsq,
                                const float* __restrict__ w, const float* __restrict__ b,
                                float2* __restrict__ ss)
{
    int f = threadIdx.x;                               // 64 threads
    double s = 0.0, s2 = 0.0;
    for (int blk = 0; blk < OLD_RED_BLOCKS; ++blk) {
        s  += psum  [blk * 64 + f];
        s2 += psumsq[blk * 64 + f];
    }
    double mu   = s / (double)N_NODES;
    double var  = s2 / (double)N_NODES - mu * mu;
    double rstd = 1.0 / sqrt(var + EPS_BN);
    float sc = (float)rstd * w[f];
    float2 o; o.x = sc; o.y = b[f] - (float)mu * sc;
    ss[f] = o;
}

// ------------------------------------------------------- BN apply -----------
__global__ void __launch_bounds__(256) bn_apply2(
    float* __restrict__ out, const float2* __restrict__ ss)
{
    __shared__ float sS[64], sH[64];
    if (threadIdx.x < 64) {
        float2 p = ss[threadIdx.x];
        sS[threadIdx.x] = p.x; sH[threadIdx.x] = p.y;
    }
    __syncthreads();
    const size_t i4 = ((size_t)blockIdx.x * 256 + threadIdx.x) * 4;   // grid exact
    float4 v = *reinterpret_cast<const float4*>(out + i4);
    const int f = (int)(i4 & 63);
    v.x = v.x * sS[f + 0] + sH[f + 0];
    v.y = v.y * sS[f + 1] + sH[f + 1];
    v.z = v.z * sS[f + 2] + sH[f + 2];
    v.w = v.w * sS[f + 3] + sH[f + 3];
    *reinterpret_cast<float4*>(out + i4) = v;
}

// ---------------------------------------------------------------------------
extern "C" void kernel_launch(void* const* d_in, const int* in_sizes, int n_in,
                              void* d_out, int out_size, void* d_ws, size_t ws_size,
                              hipStream_t stream) {
    const float* h    = (const float*)d_in[0];
    const float* norm = (const float*)d_in[1];
    /* d_in[2] = e, unused */
    const float* bnw  = (const float*)d_in[3];
    const float* bnb  = (const float*)d_in[4];
    const int*   src  = (const int*)d_in[5];
    const int*   dst  = (const int*)d_in[6];
    float* out = (float*)d_out;

    char* ws = (char*)d_ws;
    size_t o = 0;
    __half* hnbuf = (__half*)(ws + o);
    o += (((size_t)N_NODES * FEAT * sizeof(__half)) + 255) & ~(size_t)255;    // 12.8 MB
    int* rowptr = (int*)(ws + o);
    o += (((size_t)(N_NODES + 1) * sizeof(int)) + 255) & ~(size_t)255;        // 0.4 MB
    float2* ss = (float2*)(ws + o); o += 512;
    float2* partial = (float2*)(ws + o);
    o += (size_t)STAT1_BLOCKS * 64 * sizeof(float2);                           // 128 KB
    // new path: block-major float2 pstat[AGG_BLOCKS][64]
    float2* pstat = (float2*)(ws + o);
    const size_t need_new = o + (size_t)AGG_BLOCKS * 64 * sizeof(float2);      // +6.4 MB
    // fallback path: psum/psumsq doubles (reuse same region)
    double* psum   = (double*)(ws + o);
    double* psumsq = (double*)(ws + o + (size_t)OLD_RED_BLOCKS * 64 * sizeof(double));

    prep<<<HN_BLOCKS + SC_BLOCKS, 256, 0, stream>>>(h, norm, dst, hnbuf, rowptr);

    if (ws_size >= need_new) {
        pna_agg6<true><<<AGG_BLOCKS, 256, 0, stream>>>(hnbuf, norm, src, rowptr, out, pstat);
        bn_stats1<<<STAT1_BLOCKS, 256, 0, stream>>>(pstat, partial);
        bn_stats2<<<1, 256, 0, stream>>>(partial, bnw, bnb, ss);
    } else {
        pna_agg6<false><<<AGG_BLOCKS, 256, 0, stream>>>(hnbuf, norm, src, rowptr, out, nullptr);
        bn_partial<<<OLD_RED_BLOCKS, 256, 0, stream>>>(out, psum, psumsq);
        bn_finalize_old<<<1, 64, 0, stream>>>(psum, psumsq, bnw, bnb, ss);
    }
    bn_apply2<<<HN_BLOCKS, 256, 0, stream>>>(out, ss);
}

// Round 12
// 82.980 us; speedup vs baseline: 1.0623x; 1.0155x over previous
//
#include <hip/hip_runtime.h>
#include <hip/hip_fp16.h>
#include <math.h>
#include <float.h>

#define N_NODES 100000
#define N_EDGES 1200000
#define FEAT 64
#define AVG_D_LOG 2.5649493574615367f  /* log(13.0) */
#define EPS_STD 1e-5f
#define EPS_BN 1e-5
#define AGG_BLOCKS 12500               /* 2 nodes/wave * 4 waves: 12500*8 = N_NODES */
#define HN_BLOCKS 6250                 /* N_NODES*FEAT/4/256 */
#define SC_BLOCKS 4688                 /* ceil(N_EDGES/256) edge-scatter blocks */
#define STAT1_BLOCKS 256
#define ROWS1 49                       /* ceil(12500/256) */

typedef _Float16 h2v __attribute__((ext_vector_type(2)));

#if __has_builtin(__builtin_fmaxf16)
#define H16MAX(a,b) __builtin_fmaxf16((a),(b))
#define H16MIN(a,b) __builtin_fminf16((a),(b))
#else
#define H16MAX(a,b) ((a) > (b) ? (a) : (b))
#define H16MIN(a,b) ((a) < (b) ? (a) : (b))
#endif

static __device__ __forceinline__ h2v h2vmax(h2v a, h2v b) {
#if __has_builtin(__builtin_elementwise_max)
    return __builtin_elementwise_max(a, b);
#else
    h2v r; r.x = H16MAX(a.x, b.x); r.y = H16MAX(a.y, b.y); return r;
#endif
}
static __device__ __forceinline__ h2v h2vmin(h2v a, h2v b) {
#if __has_builtin(__builtin_elementwise_min)
    return __builtin_elementwise_min(a, b);
#else
    h2v r; r.x = H16MIN(a.x, b.x); r.y = H16MIN(a.y, b.y); return r;
#endif
}
#if __has_builtin(__builtin_amdgcn_fdot2)
#define FDOT2(a,b,c) __builtin_amdgcn_fdot2((a),(b),(c),false)
#else
#define FDOT2(a,b,c) (__builtin_fmaf((float)(a).x,(float)(b).x, __builtin_fmaf((float)(a).y,(float)(b).y,(c))))
#endif

// ------------------------- fused hn(fp16) + rowptr(scatter) ----------------
__global__ void __launch_bounds__(256) prep(
    const float* __restrict__ h, const float* __restrict__ norm,
    const int* __restrict__ dst,
    __half* __restrict__ hn_h, int* __restrict__ rowptr)
{
    const int b = blockIdx.x;
    if (b < HN_BLOCKS) {
        const size_t i4 = ((size_t)b * 256 + threadIdx.x) * 4;
        const int node = (int)(i4 >> 6);
        const float nr = norm[node];
        float4 v = *reinterpret_cast<const float4*>(h + i4);
        __half2 p0 = __floats2half2_rn(v.x * nr, v.y * nr);
        __half2 p1 = __floats2half2_rn(v.z * nr, v.w * nr);
        __half2* o = reinterpret_cast<__half2*>(hn_h + i4);
        o[0] = p0; o[1] = p1;
    } else {
        const int i = (b - HN_BLOCKS) * 256 + threadIdx.x;
        if (i >= N_EDGES) return;
        const int d1 = dst[i];
        const int d0 = (i == 0) ? -1 : dst[i - 1];
        for (int n = d0 + 1; n <= d1; ++n) rowptr[n] = i;
        if (i == N_EDGES - 1) {
            for (int n = d1 + 1; n <= N_NODES; ++n) rowptr[n] = N_EDGES;
        }
    }
}

// ------------------------------------------------------- aggregation --------
// One wave = two consecutive nodes. Lane = feature. Edge PAIRS packed into
// half2 (d16/d16_hi loads); s1/s2 via v_dot2_f32_f16 (f32 accum), max/min via
// v_pk_max/min_f16. Dual A/B batches keep 16 loads in flight.
// OUT16: write pre-BN values as fp16 to ws (halves agg-write + apply-read).
template <bool OUT16>
__global__ void __launch_bounds__(256) pna_agg7(
    const __half* __restrict__ hn, const float* __restrict__ norm,
    const int* __restrict__ src, const int* __restrict__ rowptr,
    float* __restrict__ outf, __half* __restrict__ outh,
    float2* __restrict__ pstat)
{
    const int tid  = threadIdx.x;
    const int wid  = tid >> 6;
    const int lane = tid & 63;
    const int n0   = (blockIdx.x * 4 + wid) * 2;       // n0, n0+1 < N_NODES

    const int s0 = __builtin_amdgcn_readfirstlane(rowptr[n0]);
    const int e0 = __builtin_amdgcn_readfirstlane(rowptr[n0 + 1]);
    const int e1 = __builtin_amdgcn_readfirstlane(rowptr[n0 + 2]);
    const int degA = e0 - s0;
    const int degB = e1 - e0;

    const _Float16* __restrict__ hnf = (const _Float16*)hn;
    const float ownA = (float)hnf[(size_t)n0 * FEAT + lane];
    const float ownB = (float)hnf[(size_t)(n0 + 1) * FEAT + lane];

    float s1A = 0.f, s2A = 0.f, s1B = 0.f, s2B = 0.f;
    h2v mxA = { (_Float16)(-65504.f), (_Float16)(-65504.f) };
    h2v mnA = { (_Float16)( 65504.f), (_Float16)( 65504.f) };
    h2v mxB = mxA, mnB = mnA;
    const h2v ones = { (_Float16)1.f, (_Float16)1.f };

#define LOADP(J0,J1) ({ h2v w__;                                   \
        w__.x = hnf[(size_t)(J0) * FEAT + lane];                   \
        w__.y = hnf[(size_t)(J1) * FEAT + lane]; w__; })
#define ACCA(W) do { h2v w_ = (W);                                 \
        s1A = FDOT2(w_, ones, s1A); s2A = FDOT2(w_, w_, s2A);      \
        mxA = h2vmax(mxA, w_); mnA = h2vmin(mnA, w_); } while (0)
#define ACCB(W) do { h2v w_ = (W);                                 \
        s1B = FDOT2(w_, ones, s1B); s2B = FDOT2(w_, w_, s2B);      \
        mxB = h2vmax(mxB, w_); mnB = h2vmin(mnB, w_); } while (0)
#define ACCA1(W) do { _Float16 h_ = (W); float f_ = (float)h_;     \
        s1A += f_; s2A = __builtin_fmaf(f_, f_, s2A);              \
        mxA.x = H16MAX(mxA.x, h_); mnA.x = H16MIN(mnA.x, h_); } while (0)
#define ACCB1(W) do { _Float16 h_ = (W); float f_ = (float)h_;     \
        s1B += f_; s2B = __builtin_fmaf(f_, f_, s2B);              \
        mxB.x = H16MAX(mxB.x, h_); mnB.x = H16MIN(mnB.x, h_); } while (0)

    int ea = s0, eb = e0;
    // dual-8: 16 scalar loads in flight, 4 packed ACCs each side
    while (ea + 8 <= e0 && eb + 8 <= e1) {
        const int a0 = src[ea+0], a1 = src[ea+1], a2 = src[ea+2], a3 = src[ea+3];
        const int a4 = src[ea+4], a5 = src[ea+5], a6 = src[ea+6], a7 = src[ea+7];
        const int b0 = src[eb+0], b1 = src[eb+1], b2 = src[eb+2], b3 = src[eb+3];
        const int b4 = src[eb+4], b5 = src[eb+5], b6 = src[eb+6], b7 = src[eb+7];
        h2v wa01 = LOADP(a0,a1), wa23 = LOADP(a2,a3), wa45 = LOADP(a4,a5), wa67 = LOADP(a6,a7);
        h2v wb01 = LOADP(b0,b1), wb23 = LOADP(b2,b3), wb45 = LOADP(b4,b5), wb67 = LOADP(b6,b7);
        ACCA(wa01); ACCA(wa23); ACCA(wa45); ACCA(wa67);
        ACCB(wb01); ACCB(wb23); ACCB(wb45); ACCB(wb67);
        ea += 8; eb += 8;
    }
    // dual-4
    while (ea + 4 <= e0 && eb + 4 <= e1) {
        const int a0 = src[ea+0], a1 = src[ea+1], a2 = src[ea+2], a3 = src[ea+3];
        const int b0 = src[eb+0], b1 = src[eb+1], b2 = src[eb+2], b3 = src[eb+3];
        h2v wa01 = LOADP(a0,a1), wa23 = LOADP(a2,a3);
        h2v wb01 = LOADP(b0,b1), wb23 = LOADP(b2,b3);
        ACCA(wa01); ACCA(wa23);
        ACCB(wb01); ACCB(wb23);
        ea += 4; eb += 4;
    }
    // drain A: packed pairs then scalar tail
    for (; ea + 2 <= e0; ea += 2) {
        const int a0 = src[ea], a1 = src[ea+1];
        h2v w = LOADP(a0, a1);
        ACCA(w);
    }
    if (ea < e0) { ACCA1(hnf[(size_t)src[ea] * FEAT + lane]); }
    // drain B
    for (; eb + 2 <= e1; eb += 2) {
        const int b0 = src[eb], b1 = src[eb+1];
        h2v w = LOADP(b0, b1);
        ACCB(w);
    }
    if (eb < e1) { ACCB1(hnf[(size_t)src[eb] * FEAT + lane]); }
#undef LOADP
#undef ACCA
#undef ACCB
#undef ACCA1
#undef ACCB1

    float vA, vB;
    {
        float pre;
        if (degA > 0) {
            const float invd = 1.0f / (float)degA;
            const float mean = s1A * invd;
            const float var  = fmaxf(s2A * invd - mean * mean, 0.f);
            const float stdv = sqrtf(var + EPS_STD);
            const float mxf  = fmaxf((float)mxA.x, (float)mxA.y);
            const float mnf  = fminf((float)mnA.x, (float)mnA.y);
            const float logD = logf((float)degA + 1.0f);
            const float factor = norm[n0] * (1.0f + logD * (1.0f / AVG_D_LOG) + AVG_D_LOG / logD)
                                         * (1.0f / 13.0f);
            pre = ownA * (1.0f / 13.0f) + (mean + mxf + mnf + stdv) * factor;
        } else {
            pre = ownA * (1.0f / 13.0f);
        }
        vA = fmaxf(pre, 0.f);
    }
    {
        float pre;
        if (degB > 0) {
            const float invd = 1.0f / (float)degB;
            const float mean = s1B * invd;
            const float var  = fmaxf(s2B * invd - mean * mean, 0.f);
            const float stdv = sqrtf(var + EPS_STD);
            const float mxf  = fmaxf((float)mxB.x, (float)mxB.y);
            const float mnf  = fminf((float)mnB.x, (float)mnB.y);
            const float logD = logf((float)degB + 1.0f);
            const float factor = norm[n0 + 1] * (1.0f + logD * (1.0f / AVG_D_LOG) + AVG_D_LOG / logD)
                                             * (1.0f / 13.0f);
            pre = ownB * (1.0f / 13.0f) + (mean + mxf + mnf + stdv) * factor;
        } else {
            pre = ownB * (1.0f / 13.0f);
        }
        vB = fmaxf(pre, 0.f);
    }

    if (OUT16) {
        outh[(size_t)n0 * FEAT + lane]       = __float2half_rn(vA);
        outh[(size_t)(n0 + 1) * FEAT + lane] = __float2half_rn(vB);
    } else {
        outf[(size_t)n0 * FEAT + lane]       = vA;
        outf[(size_t)(n0 + 1) * FEAT + lane] = vB;
    }

    {
        __shared__ float lsS[4][64];
        __shared__ float lsQ[4][64];
        lsS[wid][lane] = vA + vB;
        lsQ[wid][lane] = vA * vA + vB * vB;
        __syncthreads();
        if (tid < 64) {
            float2 p;
            p.x = lsS[0][tid] + lsS[1][tid] + lsS[2][tid] + lsS[3][tid];
            p.y = lsQ[0][tid] + lsQ[1][tid] + lsQ[2][tid] + lsQ[3][tid];
            pstat[(size_t)blockIdx.x * 64 + tid] = p;     // coalesced 512B/block
        }
    }
}

// ------------- BN stats stage 1: coalesced slab reduce (fixed order) -------
__global__ void __launch_bounds__(256) bn_stats1(
    const float2* __restrict__ pstat, float2* __restrict__ partial)
{
    const int tid  = threadIdx.x;
    const int w    = tid >> 6;
    const int lane = tid & 63;                         // lane == feature
    const int r0 = (int)blockIdx.x * ROWS1;
    const int r1 = min(r0 + ROWS1, AGG_BLOCKS);
    float S = 0.f, Q = 0.f;
    for (int r = r0 + w; r < r1; r += 4) {             // coalesced 512B rows
        float2 p = pstat[(size_t)r * 64 + lane];
        S += p.x; Q += p.y;
    }
    __shared__ float sS[4][64], sQ[4][64];
    sS[w][lane] = S; sQ[w][lane] = Q;
    __syncthreads();
    if (tid < 64) {
        float2 o;
        o.x = sS[0][tid] + sS[1][tid] + sS[2][tid] + sS[3][tid];
        o.y = sQ[0][tid] + sQ[1][tid] + sQ[2][tid] + sQ[3][tid];
        partial[(size_t)blockIdx.x * 64 + tid] = o;
    }
}

// ------------- BN stats stage 2: fold partials -> scale/shift --------------
__global__ void __launch_bounds__(256) bn_stats2(
    const float2* __restrict__ partial,
    const float* __restrict__ w, const float* __restrict__ b,
    float2* __restrict__ ss)
{
    const int tid = threadIdx.x;
    const int g   = tid >> 6;
    const int f   = tid & 63;
    double S = 0.0, Q = 0.0;
    for (int blk = g; blk < STAT1_BLOCKS; blk += 4) {  // fixed order per thread
        float2 p = partial[(size_t)blk * 64 + f];
        S += (double)p.x; Q += (double)p.y;
    }
    __shared__ double dS[4][64], dQ[4][64];
    dS[g][f] = S; dQ[g][f] = Q;
    __syncthreads();
    if (tid < 64) {
        double s = dS[0][tid] + dS[1][tid] + dS[2][tid] + dS[3][tid];
        double q = dQ[0][tid] + dQ[1][tid] + dQ[2][tid] + dQ[3][tid];
        double mu   = s / (double)N_NODES;
        double var  = q / (double)N_NODES - mu * mu;
        double rstd = 1.0 / sqrt(var + EPS_BN);
        float sc = (float)rstd * w[tid];
        float2 o; o.x = sc; o.y = b[tid] - (float)mu * sc;
        ss[tid] = o;
    }
}

// ------------------------------------------------- BN apply (fp16 in) ------
__global__ void __launch_bounds__(256) bn_apply3(
    const __half* __restrict__ out1h, float* __restrict__ out,
    const float2* __restrict__ ss)
{
    __shared__ float sS[64], sH[64];
    if (threadIdx.x < 64) {
        float2 p = ss[threadIdx.x];
        sS[threadIdx.x] = p.x; sH[threadIdx.x] = p.y;
    }
    __syncthreads();
    const size_t i4 = ((size_t)blockIdx.x * 256 + threadIdx.x) * 4;   // grid exact
    const __half2* ip = reinterpret_cast<const __half2*>(out1h + i4);
    __half2 a = ip[0], b = ip[1];
    const int f = (int)(i4 & 63);
    float4 v;
    v.x = __low2float(a)  * sS[f + 0] + sH[f + 0];
    v.y = __high2float(a) * sS[f + 1] + sH[f + 1];
    v.z = __low2float(b)  * sS[f + 2] + sH[f + 2];
    v.w = __high2float(b) * sS[f + 3] + sH[f + 3];
    *reinterpret_cast<float4*>(out + i4) = v;
}

// ------------------------------------------------- BN apply (f32 in-place) -
__global__ void __launch_bounds__(256) bn_apply2(
    float* __restrict__ out, const float2* __restrict__ ss)
{
    __shared__ float sS[64], sH[64];
    if (threadIdx.x < 64) {
        float2 p = ss[threadIdx.x];
        sS[threadIdx.x] = p.x; sH[threadIdx.x] = p.y;
    }
    __syncthreads();
    const size_t i4 = ((size_t)blockIdx.x * 256 + threadIdx.x) * 4;   // grid exact
    float4 v = *reinterpret_cast<const float4*>(out + i4);
    const int f = (int)(i4 & 63);
    v.x = v.x * sS[f + 0] + sH[f + 0];
    v.y = v.y * sS[f + 1] + sH[f + 1];
    v.z = v.z * sS[f + 2] + sH[f + 2];
    v.w = v.w * sS[f + 3] + sH[f + 3];
    *reinterpret_cast<float4*>(out + i4) = v;
}

// ---------------------------------------------------------------------------
extern "C" void kernel_launch(void* const* d_in, const int* in_sizes, int n_in,
                              void* d_out, int out_size, void* d_ws, size_t ws_size,
                              hipStream_t stream) {
    const float* h    = (const float*)d_in[0];
    const float* norm = (const float*)d_in[1];
    /* d_in[2] = e, unused */
    const float* bnw  = (const float*)d_in[3];
    const float* bnb  = (const float*)d_in[4];
    const int*   src  = (const int*)d_in[5];
    const int*   dst  = (const int*)d_in[6];
    float* out = (float*)d_out;

    char* ws = (char*)d_ws;
    size_t o = 0;
    __half* hnbuf = (__half*)(ws + o);
    o += (((size_t)N_NODES * FEAT * sizeof(__half)) + 255) & ~(size_t)255;    // 12.8 MB
    int* rowptr = (int*)(ws + o);
    o += (((size_t)(N_NODES + 1) * sizeof(int)) + 255) & ~(size_t)255;        // 0.4 MB
    float2* ss = (float2*)(ws + o); o += 512;
    float2* partial = (float2*)(ws + o);
    o += (size_t)STAT1_BLOCKS * 64 * sizeof(float2);                           // 128 KB
    float2* pstat = (float2*)(ws + o);
    o += (size_t)AGG_BLOCKS * 64 * sizeof(float2);                             // 6.4 MB
    const size_t need_mid = o;
    __half* out1h = (__half*)(ws + o);
    const size_t need_fast = o + (size_t)N_NODES * FEAT * sizeof(__half);      // +12.8 MB

    prep<<<HN_BLOCKS + SC_BLOCKS, 256, 0, stream>>>(h, norm, dst, hnbuf, rowptr);

    if (ws_size >= need_fast) {
        pna_agg7<true><<<AGG_BLOCKS, 256, 0, stream>>>(hnbuf, norm, src, rowptr,
                                                       nullptr, out1h, pstat);
        bn_stats1<<<STAT1_BLOCKS, 256, 0, stream>>>(pstat, partial);
        bn_stats2<<<1, 256, 0, stream>>>(partial, bnw, bnb, ss);
        bn_apply3<<<HN_BLOCKS, 256, 0, stream>>>(out1h, out, ss);
    } else if (ws_size >= need_mid) {
        pna_agg7<false><<<AGG_BLOCKS, 256, 0, stream>>>(hnbuf, norm, src, rowptr,
                                                        out, nullptr, pstat);
        bn_stats1<<<STAT1_BLOCKS, 256, 0, stream>>>(pstat, partial);
        bn_stats2<<<1, 256, 0, stream>>>(partial, bnw, bnb, ss);
        bn_apply2<<<HN_BLOCKS, 256, 0, stream>>>(out, ss);
    }
}

// Round 13
// 77.164 us; speedup vs baseline: 1.1424x; 1.0754x over previous
//
#include <hip/hip_runtime.h>
#include <hip/hip_fp16.h>
#include <math.h>
#include <float.h>

#define N_NODES 100000
#define N_EDGES 1200000
#define FEAT 64
#define AVG_D_LOG 2.5649493574615367   /* log(13.0) */
#define EPS_STD 1e-5f
#define EPS_BN 1e-5
#define AGG_BLOCKS 12500               /* 2 nodes/wave * 4 waves: 12500*8 = N_NODES */
#define HN_BLOCKS 6250                 /* N_NODES*FEAT/4/256 */
#define SC_BLOCKS 4688                 /* ceil(N_EDGES/256) edge-scatter blocks */
#define TAB_N 256

typedef _Float16 h2v __attribute__((ext_vector_type(2)));

#if __has_builtin(__builtin_fmaxf16)
#define H16MAX(a,b) __builtin_fmaxf16((a),(b))
#define H16MIN(a,b) __builtin_fminf16((a),(b))
#else
#define H16MAX(a,b) ((a) > (b) ? (a) : (b))
#define H16MIN(a,b) ((a) < (b) ? (a) : (b))
#endif

static __device__ __forceinline__ h2v h2vmax(h2v a, h2v b) {
#if __has_builtin(__builtin_elementwise_max)
    return __builtin_elementwise_max(a, b);
#else
    h2v r; r.x = H16MAX(a.x, b.x); r.y = H16MAX(a.y, b.y); return r;
#endif
}
static __device__ __forceinline__ h2v h2vmin(h2v a, h2v b) {
#if __has_builtin(__builtin_elementwise_min)
    return __builtin_elementwise_min(a, b);
#else
    h2v r; r.x = H16MIN(a.x, b.x); r.y = H16MIN(a.y, b.y); return r;
#endif
}
#if __has_builtin(__builtin_amdgcn_fdot2)
#define FDOT2(a,b,c) __builtin_amdgcn_fdot2((a),(b),(c),false)
#else
#define FDOT2(a,b,c) (__builtin_fmaf((float)(a).x,(float)(b).x, __builtin_fmaf((float)(a).y,(float)(b).y,(c))))
#endif

// ---------------- fused hn(fp16) + rowptr(scatter) + degree table ----------
__global__ void __launch_bounds__(256) prep(
    const float* __restrict__ h, const float* __restrict__ norm,
    const int* __restrict__ dst,
    __half* __restrict__ hn_h, int* __restrict__ rowptr,
    float2* __restrict__ tab)
{
    const int b = blockIdx.x;
    if (b < HN_BLOCKS) {
        const size_t i4 = ((size_t)b * 256 + threadIdx.x) * 4;
        const int node = (int)(i4 >> 6);
        const float nr = norm[node];
        float4 v = *reinterpret_cast<const float4*>(h + i4);
        __half2 p0 = __floats2half2_rn(v.x * nr, v.y * nr);
        __half2 p1 = __floats2half2_rn(v.z * nr, v.w * nr);
        __half2* o = reinterpret_cast<__half2*>(hn_h + i4);
        o[0] = p0; o[1] = p1;
    } else if (b < HN_BLOCKS + SC_BLOCKS) {
        const int i = (b - HN_BLOCKS) * 256 + threadIdx.x;
        if (i >= N_EDGES) return;
        const int d1 = dst[i];
        const int d0 = (i == 0) ? -1 : dst[i - 1];
        for (int n = d0 + 1; n <= d1; ++n) rowptr[n] = i;
        if (i == N_EDGES - 1) {
            for (int n = d1 + 1; n <= N_NODES; ++n) rowptr[n] = N_EDGES;
        }
    } else {
        const int d = threadIdx.x;                      // 0..255
        double invd = (d > 0) ? 1.0 / (double)d : 1.0;
        double fb = 0.0;
        if (d > 0) {
            double lg = log((double)d + 1.0);
            fb = (1.0 + lg / AVG_D_LOG + AVG_D_LOG / lg) / 13.0;
        }
        float2 t; t.x = (float)invd; t.y = (float)fb;
        tab[d] = t;
    }
}

// ------------------------------------------------------- aggregation --------
// One wave = two consecutive nodes. Lane = feature. Edge PAIRS packed into
// half2; s1/s2 via v_dot2_f32_f16 (f32 accum); pk max/min. Dual A/B batches
// keep 16 loads in flight. Epilogue uses the deg table (no logf/div).
template <bool OUT16>
__global__ void __launch_bounds__(256) pna_agg8(
    const __half* __restrict__ hn, const float* __restrict__ norm,
    const int* __restrict__ src, const int* __restrict__ rowptr,
    const float2* __restrict__ tab,
    float* __restrict__ outf, __half* __restrict__ outh,
    __half2* __restrict__ pstat)
{
    const int tid  = threadIdx.x;
    const int wid  = tid >> 6;
    const int lane = tid & 63;
    const int n0   = (blockIdx.x * 4 + wid) * 2;       // n0, n0+1 < N_NODES

    const int s0 = __builtin_amdgcn_readfirstlane(rowptr[n0]);
    const int e0 = __builtin_amdgcn_readfirstlane(rowptr[n0 + 1]);
    const int e1 = __builtin_amdgcn_readfirstlane(rowptr[n0 + 2]);
    const int degA = e0 - s0;
    const int degB = e1 - e0;

    const _Float16* __restrict__ hnf = (const _Float16*)hn;
    const float ownA = (float)hnf[(size_t)n0 * FEAT + lane];
    const float ownB = (float)hnf[(size_t)(n0 + 1) * FEAT + lane];

    float s1A = 0.f, s2A = 0.f, s1B = 0.f, s2B = 0.f;
    h2v mxA = { (_Float16)(-65504.f), (_Float16)(-65504.f) };
    h2v mnA = { (_Float16)( 65504.f), (_Float16)( 65504.f) };
    h2v mxB = mxA, mnB = mnA;
    const h2v ones = { (_Float16)1.f, (_Float16)1.f };

#define LOADP(J0,J1) ({ h2v w__;                                   \
        w__.x = hnf[(size_t)(J0) * FEAT + lane];                   \
        w__.y = hnf[(size_t)(J1) * FEAT + lane]; w__; })
#define ACCA(W) do { h2v w_ = (W);                                 \
        s1A = FDOT2(w_, ones, s1A); s2A = FDOT2(w_, w_, s2A);      \
        mxA = h2vmax(mxA, w_); mnA = h2vmin(mnA, w_); } while (0)
#define ACCB(W) do { h2v w_ = (W);                                 \
        s1B = FDOT2(w_, ones, s1B); s2B = FDOT2(w_, w_, s2B);      \
        mxB = h2vmax(mxB, w_); mnB = h2vmin(mnB, w_); } while (0)
#define ACCA1(W) do { _Float16 h_ = (W); float f_ = (float)h_;     \
        s1A += f_; s2A = __builtin_fmaf(f_, f_, s2A);              \
        mxA.x = H16MAX(mxA.x, h_); mnA.x = H16MIN(mnA.x, h_); } while (0)
#define ACCB1(W) do { _Float16 h_ = (W); float f_ = (float)h_;     \
        s1B += f_; s2B = __builtin_fmaf(f_, f_, s2B);              \
        mxB.x = H16MAX(mxB.x, h_); mnB.x = H16MIN(mnB.x, h_); } while (0)

    int ea = s0, eb = e0;
    while (ea + 8 <= e0 && eb + 8 <= e1) {
        const int a0 = src[ea+0], a1 = src[ea+1], a2 = src[ea+2], a3 = src[ea+3];
        const int a4 = src[ea+4], a5 = src[ea+5], a6 = src[ea+6], a7 = src[ea+7];
        const int b0 = src[eb+0], b1 = src[eb+1], b2 = src[eb+2], b3 = src[eb+3];
        const int b4 = src[eb+4], b5 = src[eb+5], b6 = src[eb+6], b7 = src[eb+7];
        h2v wa01 = LOADP(a0,a1), wa23 = LOADP(a2,a3), wa45 = LOADP(a4,a5), wa67 = LOADP(a6,a7);
        h2v wb01 = LOADP(b0,b1), wb23 = LOADP(b2,b3), wb45 = LOADP(b4,b5), wb67 = LOADP(b6,b7);
        ACCA(wa01); ACCA(wa23); ACCA(wa45); ACCA(wa67);
        ACCB(wb01); ACCB(wb23); ACCB(wb45); ACCB(wb67);
        ea += 8; eb += 8;
    }
    while (ea + 4 <= e0 && eb + 4 <= e1) {
        const int a0 = src[ea+0], a1 = src[ea+1], a2 = src[ea+2], a3 = src[ea+3];
        const int b0 = src[eb+0], b1 = src[eb+1], b2 = src[eb+2], b3 = src[eb+3];
        h2v wa01 = LOADP(a0,a1), wa23 = LOADP(a2,a3);
        h2v wb01 = LOADP(b0,b1), wb23 = LOADP(b2,b3);
        ACCA(wa01); ACCA(wa23);
        ACCB(wb01); ACCB(wb23);
        ea += 4; eb += 4;
    }
    for (; ea + 2 <= e0; ea += 2) {
        const int a0 = src[ea], a1 = src[ea+1];
        h2v w = LOADP(a0, a1);
        ACCA(w);
    }
    if (ea < e0) { ACCA1(hnf[(size_t)src[ea] * FEAT + lane]); }
    for (; eb + 2 <= e1; eb += 2) {
        const int b0 = src[eb], b1 = src[eb+1];
        h2v w = LOADP(b0, b1);
        ACCB(w);
    }
    if (eb < e1) { ACCB1(hnf[(size_t)src[eb] * FEAT + lane]); }
#undef LOADP
#undef ACCA
#undef ACCB
#undef ACCA1
#undef ACCB1

    float vA, vB;
    {
        float pre;
        if (degA > 0) {
            float invd, fb;
            if (degA < TAB_N) { float2 t = tab[degA]; invd = t.x; fb = t.y; }
            else {
                invd = 1.0f / (float)degA;
                float lg = logf((float)degA + 1.0f);
                fb = (1.0f + lg * (float)(1.0 / AVG_D_LOG) + (float)AVG_D_LOG / lg) * (1.0f / 13.0f);
            }
            const float mean = s1A * invd;
            const float var  = fmaxf(s2A * invd - mean * mean, 0.f);
            const float stdv = sqrtf(var + EPS_STD);
            const float mxf  = fmaxf((float)mxA.x, (float)mxA.y);
            const float mnf  = fminf((float)mnA.x, (float)mnA.y);
            const float factor = norm[n0] * fb;
            pre = ownA * (1.0f / 13.0f) + (mean + mxf + mnf + stdv) * factor;
        } else {
            pre = ownA * (1.0f / 13.0f);
        }
        vA = fmaxf(pre, 0.f);
    }
    {
        float pre;
        if (degB > 0) {
            float invd, fb;
            if (degB < TAB_N) { float2 t = tab[degB]; invd = t.x; fb = t.y; }
            else {
                invd = 1.0f / (float)degB;
                float lg = logf((float)degB + 1.0f);
                fb = (1.0f + lg * (float)(1.0 / AVG_D_LOG) + (float)AVG_D_LOG / lg) * (1.0f / 13.0f);
            }
            const float mean = s1B * invd;
            const float var  = fmaxf(s2B * invd - mean * mean, 0.f);
            const float stdv = sqrtf(var + EPS_STD);
            const float mxf  = fmaxf((float)mxB.x, (float)mxB.y);
            const float mnf  = fminf((float)mnB.x, (float)mnB.y);
            const float factor = norm[n0 + 1] * fb;
            pre = ownB * (1.0f / 13.0f) + (mean + mxf + mnf + stdv) * factor;
        } else {
            pre = ownB * (1.0f / 13.0f);
        }
        vB = fmaxf(pre, 0.f);
    }

    if (OUT16) {
        outh[(size_t)n0 * FEAT + lane]       = __float2half_rn(vA);
        outh[(size_t)(n0 + 1) * FEAT + lane] = __float2half_rn(vB);
    } else {
        outf[(size_t)n0 * FEAT + lane]       = vA;
        outf[(size_t)(n0 + 1) * FEAT + lane] = vB;
    }

    {
        __shared__ float lsS[4][64];
        __shared__ float lsQ[4][64];
        lsS[wid][lane] = vA + vB;
        lsQ[wid][lane] = vA * vA + vB * vB;
        __syncthreads();
        if (tid < 64) {
            float S = lsS[0][tid] + lsS[1][tid] + lsS[2][tid] + lsS[3][tid];
            float Q = lsQ[0][tid] + lsQ[1][tid] + lsQ[2][tid] + lsQ[3][tid];
            pstat[(size_t)blockIdx.x * 64 + tid] = __floats2half2_rn(S, Q);  // 256B/block
        }
    }
}

// ------- BN stats: ONE dispatch, 64 blocks (one per feature), fence-free ----
__global__ void __launch_bounds__(256) bn_statsM(
    const __half2* __restrict__ pstat,
    const float* __restrict__ w, const float* __restrict__ b,
    float2* __restrict__ ss)
{
    const int f   = (int)blockIdx.x;                   // 0..63
    const int tid = threadIdx.x;
    float S = 0.f, Q = 0.f;
    for (int i = tid; i < AGG_BLOCKS; i += 256) {      // 4B @ 256B stride, L2-hot
        __half2 p = pstat[(size_t)i * 64 + f];
        S += __low2float(p); Q += __high2float(p);
    }
    __shared__ double rs[256], rq[256];
    rs[tid] = (double)S; rq[tid] = (double)Q;
    __syncthreads();
    for (int s = 128; s > 0; s >>= 1) {
        if (tid < s) { rs[tid] += rs[tid + s]; rq[tid] += rq[tid + s]; }
        __syncthreads();
    }
    if (tid == 0) {
        double mu   = rs[0] / (double)N_NODES;
        double var  = rq[0] / (double)N_NODES - mu * mu;
        double rstd = 1.0 / sqrt(var + EPS_BN);
        float sc = (float)rstd * w[f];
        float2 o; o.x = sc; o.y = b[f] - (float)mu * sc;
        ss[f] = o;
    }
}

// ------------------------------------------------- BN apply (fp16 in) ------
__global__ void __launch_bounds__(256) bn_apply3(
    const __half* __restrict__ out1h, float* __restrict__ out,
    const float2* __restrict__ ss)
{
    __shared__ float sS[64], sH[64];
    if (threadIdx.x < 64) {
        float2 p = ss[threadIdx.x];
        sS[threadIdx.x] = p.x; sH[threadIdx.x] = p.y;
    }
    __syncthreads();
    const size_t i4 = ((size_t)blockIdx.x * 256 + threadIdx.x) * 4;   // grid exact
    const __half2* ip = reinterpret_cast<const __half2*>(out1h + i4);
    __half2 a = ip[0], b = ip[1];
    const int f = (int)(i4 & 63);
    float4 v;
    v.x = __low2float(a)  * sS[f + 0] + sH[f + 0];
    v.y = __high2float(a) * sS[f + 1] + sH[f + 1];
    v.z = __low2float(b)  * sS[f + 2] + sH[f + 2];
    v.w = __high2float(b) * sS[f + 3] + sH[f + 3];
    *reinterpret_cast<float4*>(out + i4) = v;
}

// ------------------------------------------------- BN apply (f32 in-place) -
__global__ void __launch_bounds__(256) bn_apply2(
    float* __restrict__ out, const float2* __restrict__ ss)
{
    __shared__ float sS[64], sH[64];
    if (threadIdx.x < 64) {
        float2 p = ss[threadIdx.x];
        sS[threadIdx.x] = p.x; sH[threadIdx.x] = p.y;
    }
    __syncthreads();
    const size_t i4 = ((size_t)blockIdx.x * 256 + threadIdx.x) * 4;   // grid exact
    float4 v = *reinterpret_cast<const float4*>(out + i4);
    const int f = (int)(i4 & 63);
    v.x = v.x * sS[f + 0] + sH[f + 0];
    v.y = v.y * sS[f + 1] + sH[f + 1];
    v.z = v.z * sS[f + 2] + sH[f + 2];
    v.w = v.w * sS[f + 3] + sH[f + 3];
    *reinterpret_cast<float4*>(out + i4) = v;
}

// ---------------------------------------------------------------------------
extern "C" void kernel_launch(void* const* d_in, const int* in_sizes, int n_in,
                              void* d_out, int out_size, void* d_ws, size_t ws_size,
                              hipStream_t stream) {
    const float* h    = (const float*)d_in[0];
    const float* norm = (const float*)d_in[1];
    /* d_in[2] = e, unused */
    const float* bnw  = (const float*)d_in[3];
    const float* bnb  = (const float*)d_in[4];
    const int*   src  = (const int*)d_in[5];
    const int*   dst  = (const int*)d_in[6];
    float* out = (float*)d_out;

    char* ws = (char*)d_ws;
    size_t o = 0;
    __half* hnbuf = (__half*)(ws + o);
    o += (((size_t)N_NODES * FEAT * sizeof(__half)) + 255) & ~(size_t)255;    // 12.8 MB
    int* rowptr = (int*)(ws + o);
    o += (((size_t)(N_NODES + 1) * sizeof(int)) + 255) & ~(size_t)255;        // 0.4 MB
    float2* ss = (float2*)(ws + o); o += 512;
    float2* tab = (float2*)(ws + o); o += (size_t)TAB_N * sizeof(float2);     // 2 KB
    __half2* pstat = (__half2*)(ws + o);
    o += (size_t)AGG_BLOCKS * 64 * sizeof(__half2);                            // 3.2 MB
    const size_t need_mid = o;
    __half* out1h = (__half*)(ws + o);
    const size_t need_fast = o + (size_t)N_NODES * FEAT * sizeof(__half);      // +12.8 MB

    prep<<<HN_BLOCKS + SC_BLOCKS + 1, 256, 0, stream>>>(h, norm, dst, hnbuf, rowptr, tab);

    if (ws_size >= need_fast) {
        pna_agg8<true><<<AGG_BLOCKS, 256, 0, stream>>>(hnbuf, norm, src, rowptr, tab,
                                                       nullptr, out1h, pstat);
        bn_statsM<<<64, 256, 0, stream>>>(pstat, bnw, bnb, ss);
        bn_apply3<<<HN_BLOCKS, 256, 0, stream>>>(out1h, out, ss);
    } else if (ws_size >= need_mid) {
        pna_agg8<false><<<AGG_BLOCKS, 256, 0, stream>>>(hnbuf, norm, src, rowptr, tab,
                                                        out, nullptr, pstat);
        bn_statsM<<<64, 256, 0, stream>>>(pstat, bnw, bnb, ss);
        bn_apply2<<<HN_BLOCKS, 256, 0, stream>>>(out, ss);
    }
}

// Round 14
// 72.480 us; speedup vs baseline: 1.2162x; 1.0646x over previous
//
#include <hip/hip_runtime.h>
#include <hip/hip_fp16.h>
#include <math.h>
#include <float.h>

#define N_NODES 100000
#define N_EDGES 1200000
#define FEAT 64
#define AVG_D_LOG 2.5649493574615367   /* log(13.0) */
#define EPS_STD 1e-5f
#define EPS_BN 1e-5
#define AGG_BLOCKS 6250                /* 4 nodes/wave * 4 waves = 16/block */
#define HN_BLOCKS 6250                 /* N_NODES*FEAT/4/256 */
#define SC_BLOCKS 4688                 /* ceil(N_EDGES/256) edge-scatter blocks */
#define TAB_N 256

typedef _Float16 h2v __attribute__((ext_vector_type(2)));

#if __has_builtin(__builtin_fmaxf16)
#define H16MAX(a,b) __builtin_fmaxf16((a),(b))
#define H16MIN(a,b) __builtin_fminf16((a),(b))
#else
#define H16MAX(a,b) ((a) > (b) ? (a) : (b))
#define H16MIN(a,b) ((a) < (b) ? (a) : (b))
#endif

static __device__ __forceinline__ h2v h2vmax(h2v a, h2v b) {
#if __has_builtin(__builtin_elementwise_max)
    return __builtin_elementwise_max(a, b);
#else
    h2v r; r.x = H16MAX(a.x, b.x); r.y = H16MAX(a.y, b.y); return r;
#endif
}
static __device__ __forceinline__ h2v h2vmin(h2v a, h2v b) {
#if __has_builtin(__builtin_elementwise_min)
    return __builtin_elementwise_min(a, b);
#else
    h2v r; r.x = H16MIN(a.x, b.x); r.y = H16MIN(a.y, b.y); return r;
#endif
}
#if __has_builtin(__builtin_amdgcn_fdot2)
#define FDOT2(a,b,c) __builtin_amdgcn_fdot2((a),(b),(c),false)
#else
#define FDOT2(a,b,c) (__builtin_fmaf((float)(a).x,(float)(b).x, __builtin_fmaf((float)(a).y,(float)(b).y,(c))))
#endif

// ---------------- fused hn(fp16) + rowptr(scatter) + degree table ----------
__global__ void __launch_bounds__(256) prep(
    const float* __restrict__ h, const float* __restrict__ norm,
    const int* __restrict__ dst,
    __half* __restrict__ hn_h, int* __restrict__ rowptr,
    float2* __restrict__ tab)
{
    const int b = blockIdx.x;
    if (b < HN_BLOCKS) {
        const size_t i4 = ((size_t)b * 256 + threadIdx.x) * 4;
        const int node = (int)(i4 >> 6);
        const float nr = norm[node];
        float4 v = *reinterpret_cast<const float4*>(h + i4);
        __half2 p0 = __floats2half2_rn(v.x * nr, v.y * nr);
        __half2 p1 = __floats2half2_rn(v.z * nr, v.w * nr);
        __half2* o = reinterpret_cast<__half2*>(hn_h + i4);
        o[0] = p0; o[1] = p1;
    } else if (b < HN_BLOCKS + SC_BLOCKS) {
        const int i = (b - HN_BLOCKS) * 256 + threadIdx.x;
        if (i >= N_EDGES) return;
        const int d1 = dst[i];
        const int d0 = (i == 0) ? -1 : dst[i - 1];
        for (int n = d0 + 1; n <= d1; ++n) rowptr[n] = i;
        if (i == N_EDGES - 1) {
            for (int n = d1 + 1; n <= N_NODES; ++n) rowptr[n] = N_EDGES;
        }
    } else {
        const int d = threadIdx.x;                      // 0..255
        double invd = (d > 0) ? 1.0 / (double)d : 1.0;
        double fb = 0.0;
        if (d > 0) {
            double lg = log((double)d + 1.0);
            fb = (1.0 + lg / AVG_D_LOG + AVG_D_LOG / lg) / 13.0;
        }
        float2 t; t.x = (float)invd; t.y = (float)fb;
        tab[d] = t;
    }
}

// ------------------------------------------------------- aggregation --------
// One wave = FOUR consecutive nodes (contiguous edge ranges). Lane = feature.
// Quad-4 main loop keeps 16 gathers in flight over 4 independent cursors;
// pair/single drains. dot2 f32 accum; pk max/min; table epilogue.
template <bool OUT16>
__global__ void __launch_bounds__(256) pna_agg9(
    const __half* __restrict__ hn, const float* __restrict__ norm,
    const int* __restrict__ src, const int* __restrict__ rowptr,
    const float2* __restrict__ tab,
    float* __restrict__ outf, __half* __restrict__ outh,
    __half2* __restrict__ pstat)
{
    const int tid  = threadIdx.x;
    const int wid  = tid >> 6;
    const int lane = tid & 63;
    const int n0   = (blockIdx.x * 4 + wid) * 4;       // n0..n0+3 < N_NODES

    const int r0 = __builtin_amdgcn_readfirstlane(rowptr[n0]);
    const int r1 = __builtin_amdgcn_readfirstlane(rowptr[n0 + 1]);
    const int r2 = __builtin_amdgcn_readfirstlane(rowptr[n0 + 2]);
    const int r3 = __builtin_amdgcn_readfirstlane(rowptr[n0 + 3]);
    const int r4 = __builtin_amdgcn_readfirstlane(rowptr[n0 + 4]);

    const _Float16* __restrict__ hnf = (const _Float16*)hn;
    const float own0 = (float)hnf[(size_t)(n0 + 0) * FEAT + lane];
    const float own1 = (float)hnf[(size_t)(n0 + 1) * FEAT + lane];
    const float own2 = (float)hnf[(size_t)(n0 + 2) * FEAT + lane];
    const float own3 = (float)hnf[(size_t)(n0 + 3) * FEAT + lane];

    float s10 = 0.f, s20 = 0.f, s11 = 0.f, s21 = 0.f;
    float s12 = 0.f, s22 = 0.f, s13 = 0.f, s23 = 0.f;
    h2v mx0 = { (_Float16)(-65504.f), (_Float16)(-65504.f) };
    h2v mn0 = { (_Float16)( 65504.f), (_Float16)( 65504.f) };
    h2v mx1 = mx0, mn1 = mn0, mx2 = mx0, mn2 = mn0, mx3 = mx0, mn3 = mn0;
    const h2v ones = { (_Float16)1.f, (_Float16)1.f };

#define LOADP(J0,J1) ({ h2v w__;                                   \
        w__.x = hnf[(size_t)(J0) * FEAT + lane];                   \
        w__.y = hnf[(size_t)(J1) * FEAT + lane]; w__; })
#define LOAD1(J) (hnf[(size_t)(J) * FEAT + lane])
#define ACCP(K, W) do { h2v w_ = (W);                              \
        s1##K = FDOT2(w_, ones, s1##K); s2##K = FDOT2(w_, w_, s2##K); \
        mx##K = h2vmax(mx##K, w_); mn##K = h2vmin(mn##K, w_); } while (0)
#define ACC1(K, W) do { _Float16 h_ = (W); float f_ = (float)h_;   \
        s1##K += f_; s2##K = __builtin_fmaf(f_, f_, s2##K);        \
        mx##K.x = H16MAX(mx##K.x, h_); mn##K.x = H16MIN(mn##K.x, h_); } while (0)

    int c0 = r0, c1 = r1, c2 = r2, c3 = r3;
    const int E0 = r1, E1 = r2, E2 = r3, E3 = r4;

    // quad-4: 16 gathers in flight across 4 nodes
    while (c0 + 4 <= E0 && c1 + 4 <= E1 && c2 + 4 <= E2 && c3 + 4 <= E3) {
        const int a0 = src[c0+0], a1 = src[c0+1], a2 = src[c0+2], a3 = src[c0+3];
        const int b0 = src[c1+0], b1 = src[c1+1], b2 = src[c1+2], b3 = src[c1+3];
        const int d0 = src[c2+0], d1 = src[c2+1], d2 = src[c2+2], d3 = src[c2+3];
        const int e0 = src[c3+0], e1 = src[c3+1], e2 = src[c3+2], e3 = src[c3+3];
        h2v wa0 = LOADP(a0,a1), wa1 = LOADP(a2,a3);
        h2v wb0 = LOADP(b0,b1), wb1 = LOADP(b2,b3);
        h2v wd0 = LOADP(d0,d1), wd1 = LOADP(d2,d3);
        h2v we0 = LOADP(e0,e1), we1 = LOADP(e2,e3);
        ACCP(0, wa0); ACCP(0, wa1);
        ACCP(1, wb0); ACCP(1, wb1);
        ACCP(2, wd0); ACCP(2, wd1);
        ACCP(3, we0); ACCP(3, we1);
        c0 += 4; c1 += 4; c2 += 4; c3 += 4;
    }
    // pair drain (0,1): 8 in flight
    while (c0 + 4 <= E0 && c1 + 4 <= E1) {
        const int a0 = src[c0+0], a1 = src[c0+1], a2 = src[c0+2], a3 = src[c0+3];
        const int b0 = src[c1+0], b1 = src[c1+1], b2 = src[c1+2], b3 = src[c1+3];
        h2v wa0 = LOADP(a0,a1), wa1 = LOADP(a2,a3);
        h2v wb0 = LOADP(b0,b1), wb1 = LOADP(b2,b3);
        ACCP(0, wa0); ACCP(0, wa1);
        ACCP(1, wb0); ACCP(1, wb1);
        c0 += 4; c1 += 4;
    }
    for (; c0 + 2 <= E0; c0 += 2) { h2v w = LOADP(src[c0], src[c0+1]); ACCP(0, w); }
    if (c0 < E0) { ACC1(0, LOAD1(src[c0])); }
    for (; c1 + 2 <= E1; c1 += 2) { h2v w = LOADP(src[c1], src[c1+1]); ACCP(1, w); }
    if (c1 < E1) { ACC1(1, LOAD1(src[c1])); }
    // pair drain (2,3)
    while (c2 + 4 <= E2 && c3 + 4 <= E3) {
        const int d0 = src[c2+0], d1 = src[c2+1], d2 = src[c2+2], d3 = src[c2+3];
        const int e0 = src[c3+0], e1 = src[c3+1], e2 = src[c3+2], e3 = src[c3+3];
        h2v wd0 = LOADP(d0,d1), wd1 = LOADP(d2,d3);
        h2v we0 = LOADP(e0,e1), we1 = LOADP(e2,e3);
        ACCP(2, wd0); ACCP(2, wd1);
        ACCP(3, we0); ACCP(3, we1);
        c2 += 4; c3 += 4;
    }
    for (; c2 + 2 <= E2; c2 += 2) { h2v w = LOADP(src[c2], src[c2+1]); ACCP(2, w); }
    if (c2 < E2) { ACC1(2, LOAD1(src[c2])); }
    for (; c3 + 2 <= E3; c3 += 2) { h2v w = LOADP(src[c3], src[c3+1]); ACCP(3, w); }
    if (c3 < E3) { ACC1(3, LOAD1(src[c3])); }
#undef LOADP
#undef LOAD1
#undef ACCP
#undef ACC1

#define EPILOG(K, NODE, OWN, VOUT) do {                                        \
        const int deg_ = E##K - r##K;                                          \
        float pre_;                                                            \
        if (deg_ > 0) {                                                        \
            float invd_, fb_;                                                  \
            if (deg_ < TAB_N) { float2 t_ = tab[deg_]; invd_ = t_.x; fb_ = t_.y; } \
            else {                                                             \
                invd_ = 1.0f / (float)deg_;                                    \
                float lg_ = logf((float)deg_ + 1.0f);                          \
                fb_ = (1.0f + lg_ * (float)(1.0 / AVG_D_LOG) + (float)AVG_D_LOG / lg_) * (1.0f / 13.0f); \
            }                                                                  \
            const float mean_ = s1##K * invd_;                                 \
            const float var_  = fmaxf(s2##K * invd_ - mean_ * mean_, 0.f);     \
            const float stdv_ = sqrtf(var_ + EPS_STD);                         \
            const float mxf_  = fmaxf((float)mx##K.x, (float)mx##K.y);         \
            const float mnf_  = fminf((float)mn##K.x, (float)mn##K.y);         \
            const float factor_ = norm[NODE] * fb_;                            \
            pre_ = OWN * (1.0f / 13.0f) + (mean_ + mxf_ + mnf_ + stdv_) * factor_; \
        } else {                                                               \
            pre_ = OWN * (1.0f / 13.0f);                                       \
        }                                                                      \
        VOUT = fmaxf(pre_, 0.f);                                               \
    } while (0)

    float v0, v1, v2, v3;
    EPILOG(0, n0 + 0, own0, v0);
    EPILOG(1, n0 + 1, own1, v1);
    EPILOG(2, n0 + 2, own2, v2);
    EPILOG(3, n0 + 3, own3, v3);
#undef EPILOG

    if (OUT16) {
        outh[(size_t)(n0 + 0) * FEAT + lane] = __float2half_rn(v0);
        outh[(size_t)(n0 + 1) * FEAT + lane] = __float2half_rn(v1);
        outh[(size_t)(n0 + 2) * FEAT + lane] = __float2half_rn(v2);
        outh[(size_t)(n0 + 3) * FEAT + lane] = __float2half_rn(v3);
    } else {
        outf[(size_t)(n0 + 0) * FEAT + lane] = v0;
        outf[(size_t)(n0 + 1) * FEAT + lane] = v1;
        outf[(size_t)(n0 + 2) * FEAT + lane] = v2;
        outf[(size_t)(n0 + 3) * FEAT + lane] = v3;
    }

    {
        __shared__ float lsS[4][64];
        __shared__ float lsQ[4][64];
        lsS[wid][lane] = (v0 + v1) + (v2 + v3);
        lsQ[wid][lane] = (v0 * v0 + v1 * v1) + (v2 * v2 + v3 * v3);
        __syncthreads();
        if (tid < 64) {
            float S = lsS[0][tid] + lsS[1][tid] + lsS[2][tid] + lsS[3][tid];
            float Q = lsQ[0][tid] + lsQ[1][tid] + lsQ[2][tid] + lsQ[3][tid];
            pstat[(size_t)blockIdx.x * 64 + tid] = __floats2half2_rn(S, Q);  // 256B/block
        }
    }
}

// ------- BN stats: ONE dispatch, 64 blocks (one per feature), fence-free ----
__global__ void __launch_bounds__(256) bn_statsM(
    const __half2* __restrict__ pstat,
    const float* __restrict__ w, const float* __restrict__ b,
    float2* __restrict__ ss)
{
    const int f   = (int)blockIdx.x;                   // 0..63
    const int tid = threadIdx.x;
    float S = 0.f, Q = 0.f;
    for (int i = tid; i < AGG_BLOCKS; i += 256) {      // 4B @ 256B stride, L2/L3-hot
        __half2 p = pstat[(size_t)i * 64 + f];
        S += __low2float(p); Q += __high2float(p);
    }
    __shared__ double rs[256], rq[256];
    rs[tid] = (double)S; rq[tid] = (double)Q;
    __syncthreads();
    for (int s = 128; s > 0; s >>= 1) {
        if (tid < s) { rs[tid] += rs[tid + s]; rq[tid] += rq[tid + s]; }
        __syncthreads();
    }
    if (tid == 0) {
        double mu   = rs[0] / (double)N_NODES;
        double var  = rq[0] / (double)N_NODES - mu * mu;
        double rstd = 1.0 / sqrt(var + EPS_BN);
        float sc = (float)rstd * w[f];
        float2 o; o.x = sc; o.y = b[f] - (float)mu * sc;
        ss[f] = o;
    }
}

// ------------------------------------------------- BN apply (fp16 in) ------
__global__ void __launch_bounds__(256) bn_apply3(
    const __half* __restrict__ out1h, float* __restrict__ out,
    const float2* __restrict__ ss)
{
    __shared__ float sS[64], sH[64];
    if (threadIdx.x < 64) {
        float2 p = ss[threadIdx.x];
        sS[threadIdx.x] = p.x; sH[threadIdx.x] = p.y;
    }
    __syncthreads();
    const size_t i4 = ((size_t)blockIdx.x * 256 + threadIdx.x) * 4;   // grid exact
    const __half2* ip = reinterpret_cast<const __half2*>(out1h + i4);
    __half2 a = ip[0], b = ip[1];
    const int f = (int)(i4 & 63);
    float4 v;
    v.x = __low2float(a)  * sS[f + 0] + sH[f + 0];
    v.y = __high2float(a) * sS[f + 1] + sH[f + 1];
    v.z = __low2float(b)  * sS[f + 2] + sH[f + 2];
    v.w = __high2float(b) * sS[f + 3] + sH[f + 3];
    *reinterpret_cast<float4*>(out + i4) = v;
}

// ------------------------------------------------- BN apply (f32 in-place) -
__global__ void __launch_bounds__(256) bn_apply2(
    float* __restrict__ out, const float2* __restrict__ ss)
{
    __shared__ float sS[64], sH[64];
    if (threadIdx.x < 64) {
        float2 p = ss[threadIdx.x];
        sS[threadIdx.x] = p.x; sH[threadIdx.x] = p.y;
    }
    __syncthreads();
    const size_t i4 = ((size_t)blockIdx.x * 256 + threadIdx.x) * 4;   // grid exact
    float4 v = *reinterpret_cast<const float4*>(out + i4);
    const int f = (int)(i4 & 63);
    v.x = v.x * sS[f + 0] + sH[f + 0];
    v.y = v.y * sS[f + 1] + sH[f + 1];
    v.z = v.z * sS[f + 2] + sH[f + 2];
    v.w = v.w * sS[f + 3] + sH[f + 3];
    *reinterpret_cast<float4*>(out + i4) = v;
}

// ---------------------------------------------------------------------------
extern "C" void kernel_launch(void* const* d_in, const int* in_sizes, int n_in,
                              void* d_out, int out_size, void* d_ws, size_t ws_size,
                              hipStream_t stream) {
    const float* h    = (const float*)d_in[0];
    const float* norm = (const float*)d_in[1];
    /* d_in[2] = e, unused */
    const float* bnw  = (const float*)d_in[3];
    const float* bnb  = (const float*)d_in[4];
    const int*   src  = (const int*)d_in[5];
    const int*   dst  = (const int*)d_in[6];
    float* out = (float*)d_out;

    char* ws = (char*)d_ws;
    size_t o = 0;
    __half* hnbuf = (__half*)(ws + o);
    o += (((size_t)N_NODES * FEAT * sizeof(__half)) + 255) & ~(size_t)255;    // 12.8 MB
    int* rowptr = (int*)(ws + o);
    o += (((size_t)(N_NODES + 1) * sizeof(int)) + 255) & ~(size_t)255;        // 0.4 MB
    float2* ss = (float2*)(ws + o); o += 512;
    float2* tab = (float2*)(ws + o); o += (size_t)TAB_N * sizeof(float2);     // 2 KB
    __half2* pstat = (__half2*)(ws + o);
    o += (size_t)AGG_BLOCKS * 64 * sizeof(__half2);                            // 1.6 MB
    const size_t need_mid = o;
    __half* out1h = (__half*)(ws + o);
    const size_t need_fast = o + (size_t)N_NODES * FEAT * sizeof(__half);      // +12.8 MB

    prep<<<HN_BLOCKS + SC_BLOCKS + 1, 256, 0, stream>>>(h, norm, dst, hnbuf, rowptr, tab);

    if (ws_size >= need_fast) {
        pna_agg9<true><<<AGG_BLOCKS, 256, 0, stream>>>(hnbuf, norm, src, rowptr, tab,
                                                       nullptr, out1h, pstat);
        bn_statsM<<<64, 256, 0, stream>>>(pstat, bnw, bnb, ss);
        bn_apply3<<<HN_BLOCKS, 256, 0, stream>>>(out1h, out, ss);
    } else if (ws_size >= need_mid) {
        pna_agg9<false><<<AGG_BLOCKS, 256, 0, stream>>>(hnbuf, norm, src, rowptr, tab,
                                                        out, nullptr, pstat);
        bn_statsM<<<64, 256, 0, stream>>>(pstat, bnw, bnb, ss);
        bn_apply2<<<HN_BLOCKS, 256, 0, stream>>>(out, ss);
    }
}

// Round 15
// 71.832 us; speedup vs baseline: 1.2272x; 1.0090x over previous
//
#include <hip/hip_runtime.h>
#include <hip/hip_fp16.h>
#include <math.h>
#include <float.h>

#define N_NODES 100000
#define N_EDGES 1200000
#define FEAT 64
#define AVG_D_LOG 2.5649493574615367   /* log(13.0) */
#define EPS_STD 1e-5f
#define EPS_BN 1e-5
#define AGG_BLOCKS 6250                /* 8 waves * 2 nodes = 16 nodes/block */
#define HN_BLOCKS 6250                 /* N_NODES*FEAT/4/256 */
#define SC_BLOCKS 4688                 /* ceil(N_EDGES/256) edge-scatter blocks */
#define TAB_N 256

typedef _Float16 h2v __attribute__((ext_vector_type(2)));

#if __has_builtin(__builtin_fmaxf16)
#define H16MAX(a,b) __builtin_fmaxf16((a),(b))
#define H16MIN(a,b) __builtin_fminf16((a),(b))
#else
#define H16MAX(a,b) ((a) > (b) ? (a) : (b))
#define H16MIN(a,b) ((a) < (b) ? (a) : (b))
#endif

static __device__ __forceinline__ h2v h2vmax(h2v a, h2v b) {
#if __has_builtin(__builtin_elementwise_max)
    return __builtin_elementwise_max(a, b);
#else
    h2v r; r.x = H16MAX(a.x, b.x); r.y = H16MAX(a.y, b.y); return r;
#endif
}
static __device__ __forceinline__ h2v h2vmin(h2v a, h2v b) {
#if __has_builtin(__builtin_elementwise_min)
    return __builtin_elementwise_min(a, b);
#else
    h2v r; r.x = H16MIN(a.x, b.x); r.y = H16MIN(a.y, b.y); return r;
#endif
}
#if __has_builtin(__builtin_amdgcn_fdot2)
#define FDOT2(a,b,c) __builtin_amdgcn_fdot2((a),(b),(c),false)
#else
#define FDOT2(a,b,c) (__builtin_fmaf((float)(a).x,(float)(b).x, __builtin_fmaf((float)(a).y,(float)(b).y,(c))))
#endif

// ---------------- fused hn(fp16) + rowptr(scatter) + degree table ----------
__global__ void __launch_bounds__(256) prep(
    const float* __restrict__ h, const float* __restrict__ norm,
    const int* __restrict__ dst,
    __half* __restrict__ hn_h, int* __restrict__ rowptr,
    float2* __restrict__ tab)
{
    const int b = blockIdx.x;
    if (b < HN_BLOCKS) {
        const size_t i4 = ((size_t)b * 256 + threadIdx.x) * 4;
        const int node = (int)(i4 >> 6);
        const float nr = norm[node];
        float4 v = *reinterpret_cast<const float4*>(h + i4);
        __half2 p0 = __floats2half2_rn(v.x * nr, v.y * nr);
        __half2 p1 = __floats2half2_rn(v.z * nr, v.w * nr);
        __half2* o = reinterpret_cast<__half2*>(hn_h + i4);
        o[0] = p0; o[1] = p1;
    } else if (b < HN_BLOCKS + SC_BLOCKS) {
        const int i = (b - HN_BLOCKS) * 256 + threadIdx.x;
        if (i >= N_EDGES) return;
        const int d1 = dst[i];
        const int d0 = (i == 0) ? -1 : dst[i - 1];
        for (int n = d0 + 1; n <= d1; ++n) rowptr[n] = i;
        if (i == N_EDGES - 1) {
            for (int n = d1 + 1; n <= N_NODES; ++n) rowptr[n] = N_EDGES;
        }
    } else {
        const int d = threadIdx.x;                      // 0..255
        double invd = (d > 0) ? 1.0 / (double)d : 1.0;
        double fb = 0.0;
        if (d > 0) {
            double lg = log((double)d + 1.0);
            fb = (1.0 + lg / AVG_D_LOG + AVG_D_LOG / lg) / 13.0;
        }
        float2 t; t.x = (float)invd; t.y = (float)fb;
        tab[d] = t;
    }
}

// ------------------------------------------------------- aggregation --------
// 512-thread blocks: 8 waves, each wave = TWO consecutive nodes (the proven
// R13 dual-node loop), so grid stays at 6250 (small pstat => cheap statsM).
// Lane = feature; edge pairs packed half2; dot2 f32 accum; pk max/min;
// deg-table epilogue.
template <bool OUT16>
__global__ void __launch_bounds__(512) pna_agg10(
    const __half* __restrict__ hn, const float* __restrict__ norm,
    const int* __restrict__ src, const int* __restrict__ rowptr,
    const float2* __restrict__ tab,
    float* __restrict__ outf, __half* __restrict__ outh,
    __half2* __restrict__ pstat)
{
    const int tid  = threadIdx.x;
    const int wid  = tid >> 6;                         // 0..7
    const int lane = tid & 63;
    const int n0   = (blockIdx.x * 8 + wid) * 2;       // n0, n0+1 < N_NODES

    const int s0 = __builtin_amdgcn_readfirstlane(rowptr[n0]);
    const int e0 = __builtin_amdgcn_readfirstlane(rowptr[n0 + 1]);
    const int e1 = __builtin_amdgcn_readfirstlane(rowptr[n0 + 2]);
    const int degA = e0 - s0;
    const int degB = e1 - e0;

    const _Float16* __restrict__ hnf = (const _Float16*)hn;
    const float ownA = (float)hnf[(size_t)n0 * FEAT + lane];
    const float ownB = (float)hnf[(size_t)(n0 + 1) * FEAT + lane];

    float s1A = 0.f, s2A = 0.f, s1B = 0.f, s2B = 0.f;
    h2v mxA = { (_Float16)(-65504.f), (_Float16)(-65504.f) };
    h2v mnA = { (_Float16)( 65504.f), (_Float16)( 65504.f) };
    h2v mxB = mxA, mnB = mnA;
    const h2v ones = { (_Float16)1.f, (_Float16)1.f };

#define LOADP(J0,J1) ({ h2v w__;                                   \
        w__.x = hnf[(size_t)(J0) * FEAT + lane];                   \
        w__.y = hnf[(size_t)(J1) * FEAT + lane]; w__; })
#define ACCA(W) do { h2v w_ = (W);                                 \
        s1A = FDOT2(w_, ones, s1A); s2A = FDOT2(w_, w_, s2A);      \
        mxA = h2vmax(mxA, w_); mnA = h2vmin(mnA, w_); } while (0)
#define ACCB(W) do { h2v w_ = (W);                                 \
        s1B = FDOT2(w_, ones, s1B); s2B = FDOT2(w_, w_, s2B);      \
        mxB = h2vmax(mxB, w_); mnB = h2vmin(mnB, w_); } while (0)
#define ACCA1(W) do { _Float16 h_ = (W); float f_ = (float)h_;     \
        s1A += f_; s2A = __builtin_fmaf(f_, f_, s2A);              \
        mxA.x = H16MAX(mxA.x, h_); mnA.x = H16MIN(mnA.x, h_); } while (0)
#define ACCB1(W) do { _Float16 h_ = (W); float f_ = (float)h_;     \
        s1B += f_; s2B = __builtin_fmaf(f_, f_, s2B);              \
        mxB.x = H16MAX(mxB.x, h_); mnB.x = H16MIN(mnB.x, h_); } while (0)

    int ea = s0, eb = e0;
    while (ea + 8 <= e0 && eb + 8 <= e1) {
        const int a0 = src[ea+0], a1 = src[ea+1], a2 = src[ea+2], a3 = src[ea+3];
        const int a4 = src[ea+4], a5 = src[ea+5], a6 = src[ea+6], a7 = src[ea+7];
        const int b0 = src[eb+0], b1 = src[eb+1], b2 = src[eb+2], b3 = src[eb+3];
        const int b4 = src[eb+4], b5 = src[eb+5], b6 = src[eb+6], b7 = src[eb+7];
        h2v wa01 = LOADP(a0,a1), wa23 = LOADP(a2,a3), wa45 = LOADP(a4,a5), wa67 = LOADP(a6,a7);
        h2v wb01 = LOADP(b0,b1), wb23 = LOADP(b2,b3), wb45 = LOADP(b4,b5), wb67 = LOADP(b6,b7);
        ACCA(wa01); ACCA(wa23); ACCA(wa45); ACCA(wa67);
        ACCB(wb01); ACCB(wb23); ACCB(wb45); ACCB(wb67);
        ea += 8; eb += 8;
    }
    while (ea + 4 <= e0 && eb + 4 <= e1) {
        const int a0 = src[ea+0], a1 = src[ea+1], a2 = src[ea+2], a3 = src[ea+3];
        const int b0 = src[eb+0], b1 = src[eb+1], b2 = src[eb+2], b3 = src[eb+3];
        h2v wa01 = LOADP(a0,a1), wa23 = LOADP(a2,a3);
        h2v wb01 = LOADP(b0,b1), wb23 = LOADP(b2,b3);
        ACCA(wa01); ACCA(wa23);
        ACCB(wb01); ACCB(wb23);
        ea += 4; eb += 4;
    }
    for (; ea + 2 <= e0; ea += 2) {
        h2v w = LOADP(src[ea], src[ea+1]);
        ACCA(w);
    }
    if (ea < e0) { ACCA1(hnf[(size_t)src[ea] * FEAT + lane]); }
    for (; eb + 2 <= e1; eb += 2) {
        h2v w = LOADP(src[eb], src[eb+1]);
        ACCB(w);
    }
    if (eb < e1) { ACCB1(hnf[(size_t)src[eb] * FEAT + lane]); }
#undef LOADP
#undef ACCA
#undef ACCB
#undef ACCA1
#undef ACCB1

    float vA, vB;
    {
        float pre;
        if (degA > 0) {
            float invd, fb;
            if (degA < TAB_N) { float2 t = tab[degA]; invd = t.x; fb = t.y; }
            else {
                invd = 1.0f / (float)degA;
                float lg = logf((float)degA + 1.0f);
                fb = (1.0f + lg * (float)(1.0 / AVG_D_LOG) + (float)AVG_D_LOG / lg) * (1.0f / 13.0f);
            }
            const float mean = s1A * invd;
            const float var  = fmaxf(s2A * invd - mean * mean, 0.f);
            const float stdv = sqrtf(var + EPS_STD);
            const float mxf  = fmaxf((float)mxA.x, (float)mxA.y);
            const float mnf  = fminf((float)mnA.x, (float)mnA.y);
            const float factor = norm[n0] * fb;
            pre = ownA * (1.0f / 13.0f) + (mean + mxf + mnf + stdv) * factor;
        } else {
            pre = ownA * (1.0f / 13.0f);
        }
        vA = fmaxf(pre, 0.f);
    }
    {
        float pre;
        if (degB > 0) {
            float invd, fb;
            if (degB < TAB_N) { float2 t = tab[degB]; invd = t.x; fb = t.y; }
            else {
                invd = 1.0f / (float)degB;
                float lg = logf((float)degB + 1.0f);
                fb = (1.0f + lg * (float)(1.0 / AVG_D_LOG) + (float)AVG_D_LOG / lg) * (1.0f / 13.0f);
            }
            const float mean = s1B * invd;
            const float var  = fmaxf(s2B * invd - mean * mean, 0.f);
            const float stdv = sqrtf(var + EPS_STD);
            const float mxf  = fmaxf((float)mxB.x, (float)mxB.y);
            const float mnf  = fminf((float)mnB.x, (float)mnB.y);
            const float factor = norm[n0 + 1] * fb;
            pre = ownB * (1.0f / 13.0f) + (mean + mxf + mnf + stdv) * factor;
        } else {
            pre = ownB * (1.0f / 13.0f);
        }
        vB = fmaxf(pre, 0.f);
    }

    if (OUT16) {
        outh[(size_t)n0 * FEAT + lane]       = __float2half_rn(vA);
        outh[(size_t)(n0 + 1) * FEAT + lane] = __float2half_rn(vB);
    } else {
        outf[(size_t)n0 * FEAT + lane]       = vA;
        outf[(size_t)(n0 + 1) * FEAT + lane] = vB;
    }

    {
        __shared__ float lsS[8][64];
        __shared__ float lsQ[8][64];
        lsS[wid][lane] = vA + vB;
        lsQ[wid][lane] = vA * vA + vB * vB;
        __syncthreads();
        if (tid < 64) {
            float S = (lsS[0][tid] + lsS[1][tid]) + (lsS[2][tid] + lsS[3][tid])
                    + (lsS[4][tid] + lsS[5][tid]) + (lsS[6][tid] + lsS[7][tid]);
            float Q = (lsQ[0][tid] + lsQ[1][tid]) + (lsQ[2][tid] + lsQ[3][tid])
                    + (lsQ[4][tid] + lsQ[5][tid]) + (lsQ[6][tid] + lsQ[7][tid]);
            pstat[(size_t)blockIdx.x * 64 + tid] = __floats2half2_rn(S, Q);  // 256B/block
        }
    }
}

// ------- BN stats: ONE dispatch, 64 blocks (one per feature), fence-free ----
__global__ void __launch_bounds__(256) bn_statsM(
    const __half2* __restrict__ pstat,
    const float* __restrict__ w, const float* __restrict__ b,
    float2* __restrict__ ss)
{
    const int f   = (int)blockIdx.x;                   // 0..63
    const int tid = threadIdx.x;
    float S = 0.f, Q = 0.f;
    for (int i = tid; i < AGG_BLOCKS; i += 256) {      // 4B @ 256B stride, L2/L3-hot
        __half2 p = pstat[(size_t)i * 64 + f];
        S += __low2float(p); Q += __high2float(p);
    }
    __shared__ double rs[256], rq[256];
    rs[tid] = (double)S; rq[tid] = (double)Q;
    __syncthreads();
    for (int s = 128; s > 0; s >>= 1) {
        if (tid < s) { rs[tid] += rs[tid + s]; rq[tid] += rq[tid + s]; }
        __syncthreads();
    }
    if (tid == 0) {
        double mu   = rs[0] / (double)N_NODES;
        double var  = rq[0] / (double)N_NODES - mu * mu;
        double rstd = 1.0 / sqrt(var + EPS_BN);
        float sc = (float)rstd * w[f];
        float2 o; o.x = sc; o.y = b[f] - (float)mu * sc;
        ss[f] = o;
    }
}

// ------------------------------------------------- BN apply (fp16 in) ------
__global__ void __launch_bounds__(256) bn_apply3(
    const __half* __restrict__ out1h, float* __restrict__ out,
    const float2* __restrict__ ss)
{
    __shared__ float sS[64], sH[64];
    if (threadIdx.x < 64) {
        float2 p = ss[threadIdx.x];
        sS[threadIdx.x] = p.x; sH[threadIdx.x] = p.y;
    }
    __syncthreads();
    const size_t i4 = ((size_t)blockIdx.x * 256 + threadIdx.x) * 4;   // grid exact
    const __half2* ip = reinterpret_cast<const __half2*>(out1h + i4);
    __half2 a = ip[0], b = ip[1];
    const int f = (int)(i4 & 63);
    float4 v;
    v.x = __low2float(a)  * sS[f + 0] + sH[f + 0];
    v.y = __high2float(a) * sS[f + 1] + sH[f + 1];
    v.z = __low2float(b)  * sS[f + 2] + sH[f + 2];
    v.w = __high2float(b) * sS[f + 3] + sH[f + 3];
    *reinterpret_cast<float4*>(out + i4) = v;
}

// ------------------------------------------------- BN apply (f32 in-place) -
__global__ void __launch_bounds__(256) bn_apply2(
    float* __restrict__ out, const float2* __restrict__ ss)
{
    __shared__ float sS[64], sH[64];
    if (threadIdx.x < 64) {
        float2 p = ss[threadIdx.x];
        sS[threadIdx.x] = p.x; sH[threadIdx.x] = p.y;
    }
    __syncthreads();
    const size_t i4 = ((size_t)blockIdx.x * 256 + threadIdx.x) * 4;   // grid exact
    float4 v = *reinterpret_cast<const float4*>(out + i4);
    const int f = (int)(i4 & 63);
    v.x = v.x * sS[f + 0] + sH[f + 0];
    v.y = v.y * sS[f + 1] + sH[f + 1];
    v.z = v.z * sS[f + 2] + sH[f + 2];
    v.w = v.w * sS[f + 3] + sH[f + 3];
    *reinterpret_cast<float4*>(out + i4) = v;
}

// ---------------------------------------------------------------------------
extern "C" void kernel_launch(void* const* d_in, const int* in_sizes, int n_in,
                              void* d_out, int out_size, void* d_ws, size_t ws_size,
                              hipStream_t stream) {
    const float* h    = (const float*)d_in[0];
    const float* norm = (const float*)d_in[1];
    /* d_in[2] = e, unused */
    const float* bnw  = (const float*)d_in[3];
    const float* bnb  = (const float*)d_in[4];
    const int*   src  = (const int*)d_in[5];
    const int*   dst  = (const int*)d_in[6];
    float* out = (float*)d_out;

    char* ws = (char*)d_ws;
    size_t o = 0;
    __half* hnbuf = (__half*)(ws + o);
    o += (((size_t)N_NODES * FEAT * sizeof(__half)) + 255) & ~(size_t)255;    // 12.8 MB
    int* rowptr = (int*)(ws + o);
    o += (((size_t)(N_NODES + 1) * sizeof(int)) + 255) & ~(size_t)255;        // 0.4 MB
    float2* ss = (float2*)(ws + o); o += 512;
    float2* tab = (float2*)(ws + o); o += (size_t)TAB_N * sizeof(float2);     // 2 KB
    __half2* pstat = (__half2*)(ws + o);
    o += (size_t)AGG_BLOCKS * 64 * sizeof(__half2);                            // 1.6 MB
    const size_t need_mid = o;
    __half* out1h = (__half*)(ws + o);
    const size_t need_fast = o + (size_t)N_NODES * FEAT * sizeof(__half);      // +12.8 MB

    prep<<<HN_BLOCKS + SC_BLOCKS + 1, 256, 0, stream>>>(h, norm, dst, hnbuf, rowptr, tab);

    if (ws_size >= need_fast) {
        pna_agg10<true><<<AGG_BLOCKS, 512, 0, stream>>>(hnbuf, norm, src, rowptr, tab,
                                                        nullptr, out1h, pstat);
        bn_statsM<<<64, 256, 0, stream>>>(pstat, bnw, bnb, ss);
        bn_apply3<<<HN_BLOCKS, 256, 0, stream>>>(out1h, out, ss);
    } else if (ws_size >= need_mid) {
        pna_agg10<false><<<AGG_BLOCKS, 512, 0, stream>>>(hnbuf, norm, src, rowptr, tab,
                                                         out, nullptr, pstat);
        bn_statsM<<<64, 256, 0, stream>>>(pstat, bnw, bnb, ss);
        bn_apply2<<<HN_BLOCKS, 256, 0, stream>>>(out, ss);
    }
}